// Round 9
// baseline (417.720 us; speedup 1.0000x reference)
//
#include <hip/hip_runtime.h>
#include <cstddef>

#define PI_F 3.14159265358979323846f

#define NCH 256   // C
#define NB  32    // B
#define NF  544   // n*(n/2+1),  f = i*17 + j

typedef short  bf16x8 __attribute__((ext_vector_type(8)));
typedef float  f32x4  __attribute__((ext_vector_type(4)));

// ---- workspace layout (bytes), single-chunk ----
// Afrag hosts: tmp (rfft2 out, dead before a_build) and G (after neum passes).
#define SZ_AFRAG ((size_t)NF*8*16*2*1024)       // 142,606,336
#define SZ_PBH   ((size_t)NF*NB*NCH*2)          // 8,912,896   (bf16 plane)
#define SZ_P32H  ((size_t)NF*NB*NCH*4)          // 17,825,792  (fp32 plane)
#define OFF_AFRAG ((size_t)0)
#define OFF_TBR  (OFF_AFRAG + SZ_AFRAG)
#define OFF_TBI  (OFF_TBR + SZ_PBH)
#define OFF_Z32R (OFF_TBI + SZ_PBH)
#define OFF_Z32I (OFF_Z32R + SZ_P32H)
#define OFF_WXHR (OFF_Z32I + SZ_P32H)
#define OFF_WXHI (OFF_WXHR + SZ_PBH)
#define OFF_HFRAG (OFF_WXHI + SZ_PBH)
#define SZ_HFRAG ((size_t)8*16*1024)            // 131,072
#define OFF_RED  (OFF_HFRAG + SZ_HFRAG)
#define WS_NEED  (OFF_RED + (size_t)4096)       // 214,044,672 <= 214,175,744 proven in R1

// 32-point twiddle tables: COS32[k]=cos(2pi k/32), SIN32[k]=sin(2pi k/32)
__device__ constexpr float COS32[32] = {
     1.0000000000f,  0.9807852804f,  0.9238795325f,  0.8314696123f,
     0.7071067812f,  0.5555702330f,  0.3826834324f,  0.1950903220f,
     0.0000000000f, -0.1950903220f, -0.3826834324f, -0.5555702330f,
    -0.7071067812f, -0.8314696123f, -0.9238795325f, -0.9807852804f,
    -1.0000000000f, -0.9807852804f, -0.9238795325f, -0.8314696123f,
    -0.7071067812f, -0.5555702330f, -0.3826834324f, -0.1950903220f,
    -0.0000000000f,  0.1950903220f,  0.3826834324f,  0.5555702330f,
     0.7071067812f,  0.8314696123f,  0.9238795325f,  0.9807852804f };
__device__ constexpr float SIN32[32] = {
     0.0000000000f,  0.1950903220f,  0.3826834324f,  0.5555702330f,
     0.7071067812f,  0.8314696123f,  0.9238795325f,  0.9807852804f,
     1.0000000000f,  0.9807852804f,  0.9238795325f,  0.8314696123f,
     0.7071067812f,  0.5555702330f,  0.3826834324f,  0.1950903220f,
     0.0000000000f, -0.1950903220f, -0.3826834324f, -0.5555702330f,
    -0.7071067812f, -0.8314696123f, -0.9238795325f, -0.9807852804f,
    -1.0000000000f, -0.9807852804f, -0.9238795325f, -0.8314696123f,
    -0.7071067812f, -0.5555702330f, -0.3826834324f, -0.1950903220f };

__device__ __forceinline__ unsigned short f2bf(float x) {
    unsigned int u = __float_as_uint(x);
    u += 0x7FFFu + ((u >> 16) & 1u);            // RNE
    return (unsigned short)(u >> 16);
}
__device__ __forceinline__ float bf2f(unsigned int h) {
    return __uint_as_float(h << 16);
}
__device__ __forceinline__ unsigned int pack2(float a, float b) {
    return (unsigned int)f2bf(a) | ((unsigned int)f2bf(b) << 16);
}

// ---------------- norm of wfft (closed form via Parseval) ----------------
__global__ void norm_part(const float* __restrict__ w, float* __restrict__ red) {
    int idx = blockIdx.x * 256 + threadIdx.x;
    const float* wp = w + (size_t)idx * 9;
    float s2 = 0.f, aa = 0.f, bb = 0.f;
#pragma unroll
    for (int u = 0; u < 3; u++) {
        float w0 = wp[u*3+0], w1 = wp[u*3+1], w2 = wp[u*3+2];
        s2 += w0*w0 + w1*w1 + w2*w2;
        float au = w0 + w1 + w2, bu = w0 - w1 + w2;
        aa += au*au; bb += bu*bu;
    }
    float p = 512.f*s2 + 16.f*(aa + bb);
    __shared__ float sm[256];
    sm[threadIdx.x] = p; __syncthreads();
    for (int s = 128; s > 0; s >>= 1) {
        if (threadIdx.x < s) sm[threadIdx.x] += sm[threadIdx.x + s];
        __syncthreads();
    }
    if (threadIdx.x == 0) red[blockIdx.x] = sm[0];
}

__global__ void norm_final(const float* __restrict__ red, const float* __restrict__ alpha,
                           float* __restrict__ sig) {
    __shared__ float sm[256];
    sm[threadIdx.x] = red[threadIdx.x]; __syncthreads();
    for (int s = 128; s > 0; s >>= 1) {
        if (threadIdx.x < s) sm[threadIdx.x] += sm[threadIdx.x + s];
        __syncthreads();
    }
    if (threadIdx.x == 0) sig[0] = alpha[0] / sqrtf(sm[0]);
}

// ---------------- H fragments (A-operand: m=o, k=c) ----------------
__global__ void hfrag_build(const float* __restrict__ H, unsigned short* __restrict__ Hfrag) {
    int kk = blockIdx.x, mt = blockIdx.y, lane = threadIdx.x;   // 64 threads
    int o = mt*16 + (lane & 15), c0 = kk*32 + (lane >> 4)*8;
    const float* hp = H + (size_t)o*NCH + c0;
    uint4 u;
    u.x = pack2(hp[0], hp[1]); u.y = pack2(hp[2], hp[3]);
    u.z = pack2(hp[4], hp[5]); u.w = pack2(hp[6], hp[7]);
    ((uint4*)Hfrag)[((size_t)kk*16 + mt)*64 + lane] = u;
}

// ---------------- rfft2: register-resident DFT, 8 tiles per 256-thread block ----------------
__global__ __launch_bounds__(256, 4) void rfft2_reg(const float* __restrict__ x,
                                                    float2* __restrict__ tmp)
{
    __shared__ float2 T[8][544];       // [half][r*17+j], ~35 KB
    __shared__ float wc[32], wsn[32];
    int t = threadIdx.x;
    int half = t >> 5, lane = t & 31;
    int cb = blockIdx.x * 8 + half;    // tile index in tmp order: cb = c*32 + b
    int c = cb >> 5, b = cb & 31;
    if (t < 32) { wc[t] = COS32[t]; wsn[t] = SIN32[t]; }
    float xr[32];
    const float* xp = x + ((size_t)(b * NCH + c)) * 1024 + lane * 32;
#pragma unroll
    for (int q = 0; q < 8; q++) {
        float4 v = *(const float4*)(xp + q*4);
        xr[q*4+0] = v.x; xr[q*4+1] = v.y; xr[q*4+2] = v.z; xr[q*4+3] = v.w;
    }
    // step 1: T[r=lane][j] = sum_s x[r,s] e^{-2pi i j s/32}   (constant twiddles)
#pragma unroll
    for (int j = 0; j < 17; j++) {
        float ax = 0.f, ay = 0.f;
#pragma unroll
        for (int s = 0; s < 32; s++) {
            int m = (j * s) & 31;
            ax += xr[s] * COS32[m];
            ay -= xr[s] * SIN32[m];
        }
        T[half][lane*17 + j] = make_float2(ax, ay);
    }
    __syncthreads();
    float wr_[16], wi_[16];
#pragma unroll
    for (int r = 0; r < 16; r++) {
        int m = (lane * r) & 31;
        wr_[r] = wc[m]; wi_[r] = wsn[m];
    }
    float sgn = (lane & 1) ? -1.f : 1.f;    // (-1)^i
    // step 2: z[i=lane][j] = sum_{r<16} e^{-2pi i i r/32} (T[r][j] + (-1)^i T[r+16][j])
    float2* op = tmp + (size_t)cb * 544 + lane * 17;
#pragma unroll
    for (int j = 0; j < 17; j++) {
        float ax = 0.f, ay = 0.f;
#pragma unroll
        for (int r = 0; r < 16; r++) {
            float2 t1 = T[half][r*17 + j];
            float2 t2 = T[half][(r+16)*17 + j];
            float ex = fmaf(sgn, t2.x, t1.x);
            float ey = fmaf(sgn, t2.y, t1.y);
            ax += ex * wr_[r] + ey * wi_[r];
            ay += ey * wr_[r] - ex * wi_[r];
        }
        op[j] = make_float2(ax, ay);
    }
}

// ---------------- transpose tmp[cb][f] -> fp32 planes [f][b][c] ----------------
__global__ __launch_bounds__(256) void transpose_z(const float2* __restrict__ tmp,
        float* __restrict__ z32r, float* __restrict__ z32i)
{
    __shared__ float2 tile[32][33];
    int ct = blockIdx.x, ft = blockIdx.y, b = blockIdx.z;
    int t = threadIdx.x;
#pragma unroll
    for (int it = 0; it < 4; it++) {
        int idx = t + it*256; int cl = idx >> 5, fl = idx & 31;
        tile[cl][fl] = tmp[((size_t)((ct*32 + cl)*32 + b))*544 + ft*32 + fl];
    }
    __syncthreads();
#pragma unroll
    for (int it = 0; it < 4; it++) {
        int idx = t + it*256; int fl = idx >> 5, cl = idx & 31;
        float2 v = tile[cl][fl];
        size_t zi_ = ((size_t)(ft*32 + fl)*NB + b)*NCH + ct*32 + cl;
        z32r[zi_] = v.x; z32i[zi_] = v.y;
    }
}

// ---------------- A-build into MFMA fragment order (table-lookup form) ----------------
__global__ __launch_bounds__(256) void a_build_frag(const float* __restrict__ w,
        const float* __restrict__ sig, unsigned short* __restrict__ Afrag)
{
    __shared__ float2 wtab[32];
    __shared__ unsigned short lar[512], lai[512];
    int t = threadIdx.x;
    if (t < 32) {
        float ph = -2.f * PI_F * (float)t / 32.f;
        wtab[t] = make_float2(cosf(ph), sinf(ph));
    }
    int mt = blockIdx.x, kk = blockIdx.y, fs = blockIdx.z;
    int c = mt*16 + (t & 15), cpl = t >> 4;
    int cpA = kk*32 + cpl, cpB = cpA + 16;
    float ua[9], va[9], ub[9], vb[9];
    {
        const float* pa1 = w + ((size_t)c*NCH + cpA)*9;
        const float* pb1 = w + ((size_t)c*NCH + cpB)*9;
        const float* pa2 = w + ((size_t)cpA*NCH + c)*9;
        const float* pb2 = w + ((size_t)cpB*NCH + c)*9;
#pragma unroll
        for (int q = 0; q < 9; q++) {
            float w1a = pa1[q], w2a = pa2[q], w1b = pb1[q], w2b = pb2[q];
            ua[q] = w1a - w2a; va[q] = w1a + w2a;
            ub[q] = w1b - w2b; vb[q] = w1b + w2b;
        }
    }
    float s = sig[0];
    int la_ = ((c & 15) + 16*(cpl>>3))*8 + (cpl & 7);
    int lb_ = la_ + 32*8;
    __syncthreads();
    for (int fl = fs*68; fl < fs*68 + 68; fl++) {
        int i = fl / 17, jj = fl - i * 17;    // f = i*17 + j ordering
        int m_[9];
        m_[0] = (i + jj) & 31;  m_[1] = i;             m_[2] = (i - jj) & 31;
        m_[3] = jj;             m_[4] = 0;             m_[5] = (32 - jj) & 31;
        m_[6] = (jj - i) & 31;  m_[7] = (32 - i) & 31; m_[8] = (64 - i - jj) & 31;
        float ArA = 0.f, AiA = 0.f, ArB = 0.f, AiB = 0.f;
#pragma unroll
        for (int q = 0; q < 9; q++) {
            float2 P = wtab[m_[q]];
            ArA += ua[q] * P.x; AiA += va[q] * P.y;
            ArB += ub[q] * P.x; AiB += vb[q] * P.y;
        }
        lar[la_] = f2bf(s*ArA); lai[la_] = f2bf(s*AiA);
        lar[lb_] = f2bf(s*ArB); lai[lb_] = f2bf(s*AiB);
        __syncthreads();
        size_t bch = (((size_t)fl*8 + kk)*16 + mt)*256;   // uint2 units
        ((uint2*)Afrag)[bch + t] = (t < 128) ? ((const uint2*)lar)[t]
                                             : ((const uint2*)lai)[t - 128];
        __syncthreads();
    }
}

// ---------------- neum1: t = z - A z  (z staged from fp32, identity from bf16 LDS) ----------------
__global__ __launch_bounds__(256) void neum1(
    const unsigned short* __restrict__ Afrag,
    const float* __restrict__ z32r, const float* __restrict__ z32i,
    unsigned short* __restrict__ outR, unsigned short* __restrict__ outI)
{
    __shared__ uint4 lz[2][1024];   // 32 KB, swizzled bf16
    int fl = blockIdx.x >> 1, half = blockIdx.x & 1;
    int f = fl;
    int t = threadIdx.x;
    const float4* s0 = (const float4*)(z32r + (size_t)f*8192);
    const float4* s1 = (const float4*)(z32i + (size_t)f*8192);
    for (int u = t; u < 1024; u += 256) {
        int b = u >> 5, o16 = u & 31;
        int du = b*32 + (o16 ^ (b & 7));
        float4 va = s0[u*2], vb = s0[u*2+1];
        lz[0][du] = make_uint4(pack2(va.x,va.y), pack2(va.z,va.w),
                               pack2(vb.x,vb.y), pack2(vb.z,vb.w));
        float4 vc = s1[u*2], vd = s1[u*2+1];
        lz[1][du] = make_uint4(pack2(vc.x,vc.y), pack2(vc.z,vc.w),
                               pack2(vd.x,vd.y), pack2(vd.z,vd.w));
    }
    __syncthreads();
    int w = t >> 6, lane = t & 63, lo = lane & 15, hi = lane >> 4;
    f32x4 accr[2][2], acci[2][2];
    f32x4 zz = {0.f, 0.f, 0.f, 0.f};
#pragma unroll
    for (int mt = 0; mt < 2; mt++)
#pragma unroll
        for (int nt = 0; nt < 2; nt++) { accr[mt][nt] = zz; acci[mt][nt] = zz; }
    const uint4* A4 = (const uint4*)Afrag;
    for (int kk = 0; kk < 8; kk++) {
        bf16x8 ar[2], ai[2], ain[2];
#pragma unroll
        for (int mt = 0; mt < 2; mt++) {
            int mtg = half*8 + w*2 + mt;
            size_t idx = ((((size_t)fl*8 + kk)*16 + mtg)*2)*64 + lane;
            uint4 va = A4[idx], vb = A4[idx + 64];
            ar[mt] = __builtin_bit_cast(bf16x8, va);
            ai[mt] = __builtin_bit_cast(bf16x8, vb);
            uint4 vn = make_uint4(vb.x ^ 0x80008000u, vb.y ^ 0x80008000u,
                                  vb.z ^ 0x80008000u, vb.w ^ 0x80008000u);
            ain[mt] = __builtin_bit_cast(bf16x8, vn);
        }
        bf16x8 zr[2], zi_[2];
#pragma unroll
        for (int nt = 0; nt < 2; nt++) {
            int b = nt*16 + lo;
            int du = b*32 + ((kk*4 + hi) ^ (b & 7));
            zr[nt]  = __builtin_bit_cast(bf16x8, lz[0][du]);
            zi_[nt] = __builtin_bit_cast(bf16x8, lz[1][du]);
        }
#pragma unroll
        for (int mt = 0; mt < 2; mt++)
#pragma unroll
            for (int nt = 0; nt < 2; nt++) {
                accr[mt][nt] = __builtin_amdgcn_mfma_f32_16x16x32_bf16(ar[mt],  zr[nt],  accr[mt][nt], 0, 0, 0);
                accr[mt][nt] = __builtin_amdgcn_mfma_f32_16x16x32_bf16(ain[mt], zi_[nt], accr[mt][nt], 0, 0, 0);
                acci[mt][nt] = __builtin_amdgcn_mfma_f32_16x16x32_bf16(ar[mt],  zi_[nt], acci[mt][nt], 0, 0, 0);
                acci[mt][nt] = __builtin_amdgcn_mfma_f32_16x16x32_bf16(ai[mt],  zr[nt],  acci[mt][nt], 0, 0, 0);
            }
    }
#pragma unroll
    for (int mt = 0; mt < 2; mt++)
#pragma unroll
        for (int nt = 0; nt < 2; nt++) {
            int c0 = half*128 + w*32 + mt*16 + hi*4;
            int b  = nt*16 + lo;
            int o16c = c0 >> 3;
            int duc = b*32 + (o16c ^ (b & 7));
            int sel = (c0 >> 2) & 1;
            uint2 pzr = ((const uint2*)&lz[0][duc])[sel];
            uint2 pzi = ((const uint2*)&lz[1][duc])[sel];
            float zfr[4] = { bf2f(pzr.x & 0xffffu), bf2f(pzr.x >> 16),
                             bf2f(pzr.y & 0xffffu), bf2f(pzr.y >> 16) };
            float zfi[4] = { bf2f(pzi.x & 0xffffu), bf2f(pzi.x >> 16),
                             bf2f(pzi.y & 0xffffu), bf2f(pzi.y >> 16) };
            size_t zb = ((size_t)f*NB + b)*NCH + c0;
            float vr[4], vi[4];
#pragma unroll
            for (int jj = 0; jj < 4; jj++) {
                vr[jj] = zfr[jj] - accr[mt][nt][jj];
                vi[jj] = zfi[jj] - acci[mt][nt][jj];
            }
            *(uint2*)(outR + zb) = make_uint2(pack2(vr[0], vr[1]), pack2(vr[2], vr[3]));
            *(uint2*)(outI + zb) = make_uint2(pack2(vi[0], vi[1]), pack2(vi[2], vi[3]));
        }
}

// ---------------- neum2h: wx = z32 - 2 A t  ->  wxh = H wx  (fused, full f per block) ----------------
__global__ __launch_bounds__(512) void neum2h(
    const unsigned short* __restrict__ Afrag,
    const unsigned short* __restrict__ Hfrag,
    const unsigned short* __restrict__ TR, const unsigned short* __restrict__ TI,
    const float* __restrict__ z32r, const float* __restrict__ z32i,
    unsigned short* __restrict__ wxhR, unsigned short* __restrict__ wxhI)
{
    __shared__ uint4 lz[2][1024];   // 32 KB: stages t, then reused for wx
    int fl = blockIdx.x;
    int f = fl;
    int t = threadIdx.x;
    const uint4* s0 = (const uint4*)(TR + (size_t)f*8192);
    const uint4* s1 = (const uint4*)(TI + (size_t)f*8192);
    for (int u = t; u < 2048; u += 512) {
        int p = u >> 10, idx = u & 1023;
        int b = idx >> 5, o16 = idx & 31;
        lz[p][b*32 + (o16 ^ (b & 7))] = (p ? s1 : s0)[idx];
    }
    __syncthreads();
    int w = t >> 6, lane = t & 63, lo = lane & 15, hi = lane >> 4;
    const uint4* A4 = (const uint4*)Afrag;
    const uint4* H4 = (const uint4*)Hfrag;
    f32x4 accr[2][2], acci[2][2];
    f32x4 zz = {0.f, 0.f, 0.f, 0.f};
#pragma unroll
    for (int mt = 0; mt < 2; mt++)
#pragma unroll
        for (int nt = 0; nt < 2; nt++) { accr[mt][nt] = zz; acci[mt][nt] = zz; }
    // ---- matmul 1: acc = A * t ----
    for (int kk = 0; kk < 8; kk++) {
        bf16x8 ar[2], ai[2], ain[2];
#pragma unroll
        for (int mt = 0; mt < 2; mt++) {
            int mtg = w*2 + mt;
            size_t idx = ((((size_t)fl*8 + kk)*16 + mtg)*2)*64 + lane;
            uint4 va = A4[idx], vb = A4[idx + 64];
            ar[mt] = __builtin_bit_cast(bf16x8, va);
            ai[mt] = __builtin_bit_cast(bf16x8, vb);
            uint4 vn = make_uint4(vb.x ^ 0x80008000u, vb.y ^ 0x80008000u,
                                  vb.z ^ 0x80008000u, vb.w ^ 0x80008000u);
            ain[mt] = __builtin_bit_cast(bf16x8, vn);
        }
        bf16x8 zr[2], zi_[2];
#pragma unroll
        for (int nt = 0; nt < 2; nt++) {
            int b = nt*16 + lo;
            int du = b*32 + ((kk*4 + hi) ^ (b & 7));
            zr[nt]  = __builtin_bit_cast(bf16x8, lz[0][du]);
            zi_[nt] = __builtin_bit_cast(bf16x8, lz[1][du]);
        }
#pragma unroll
        for (int mt = 0; mt < 2; mt++)
#pragma unroll
            for (int nt = 0; nt < 2; nt++) {
                accr[mt][nt] = __builtin_amdgcn_mfma_f32_16x16x32_bf16(ar[mt],  zr[nt],  accr[mt][nt], 0, 0, 0);
                accr[mt][nt] = __builtin_amdgcn_mfma_f32_16x16x32_bf16(ain[mt], zi_[nt], accr[mt][nt], 0, 0, 0);
                acci[mt][nt] = __builtin_amdgcn_mfma_f32_16x16x32_bf16(ar[mt],  zi_[nt], acci[mt][nt], 0, 0, 0);
                acci[mt][nt] = __builtin_amdgcn_mfma_f32_16x16x32_bf16(ai[mt],  zr[nt],  acci[mt][nt], 0, 0, 0);
            }
    }
    __syncthreads();   // all waves done reading t from LDS
    // ---- epilogue 1: wx = z32 - 2 acc; write bf16 wx into LDS ----
#pragma unroll
    for (int mt = 0; mt < 2; mt++)
#pragma unroll
        for (int nt = 0; nt < 2; nt++) {
            int c0 = w*32 + mt*16 + hi*4;
            int b  = nt*16 + lo;
            size_t zb = ((size_t)f*NB + b)*NCH + c0;
            float4 z4r = *(const float4*)(z32r + zb);
            float4 z4i = *(const float4*)(z32i + zb);
            float vr[4] = { z4r.x - 2.f*accr[mt][nt][0], z4r.y - 2.f*accr[mt][nt][1],
                            z4r.z - 2.f*accr[mt][nt][2], z4r.w - 2.f*accr[mt][nt][3] };
            float vi[4] = { z4i.x - 2.f*acci[mt][nt][0], z4i.y - 2.f*acci[mt][nt][1],
                            z4i.z - 2.f*acci[mt][nt][2], z4i.w - 2.f*acci[mt][nt][3] };
            int o16c = c0 >> 3;
            int duc = b*32 + (o16c ^ (b & 7));
            int sel = (c0 >> 2) & 1;
            ((uint2*)&lz[0][duc])[sel] = make_uint2(pack2(vr[0], vr[1]), pack2(vr[2], vr[3]));
            ((uint2*)&lz[1][duc])[sel] = make_uint2(pack2(vi[0], vi[1]), pack2(vi[2], vi[3]));
        }
    __syncthreads();
    // ---- matmul 2: wxh = H * wx ----
#pragma unroll
    for (int mt = 0; mt < 2; mt++)
#pragma unroll
        for (int nt = 0; nt < 2; nt++) { accr[mt][nt] = zz; acci[mt][nt] = zz; }
    for (int kk = 0; kk < 8; kk++) {
        bf16x8 hm[2];
#pragma unroll
        for (int mt = 0; mt < 2; mt++) {
            int mtg = w*2 + mt;
            hm[mt] = __builtin_bit_cast(bf16x8, H4[((size_t)kk*16 + mtg)*64 + lane]);
        }
        bf16x8 zr[2], zi_[2];
#pragma unroll
        for (int nt = 0; nt < 2; nt++) {
            int b = nt*16 + lo;
            int du = b*32 + ((kk*4 + hi) ^ (b & 7));
            zr[nt]  = __builtin_bit_cast(bf16x8, lz[0][du]);
            zi_[nt] = __builtin_bit_cast(bf16x8, lz[1][du]);
        }
#pragma unroll
        for (int mt = 0; mt < 2; mt++)
#pragma unroll
            for (int nt = 0; nt < 2; nt++) {
                accr[mt][nt] = __builtin_amdgcn_mfma_f32_16x16x32_bf16(hm[mt], zr[nt],  accr[mt][nt], 0, 0, 0);
                acci[mt][nt] = __builtin_amdgcn_mfma_f32_16x16x32_bf16(hm[mt], zi_[nt], acci[mt][nt], 0, 0, 0);
            }
    }
    // ---- epilogue 2: wxh bf16 planes, [f][b][o] layout (ob = b*256+o) ----
#pragma unroll
    for (int mt = 0; mt < 2; mt++)
#pragma unroll
        for (int nt = 0; nt < 2; nt++) {
            int o0 = w*32 + mt*16 + hi*4;
            int b  = nt*16 + lo;
            size_t zb = ((size_t)f*NB + b)*NCH + o0;
            *(uint2*)(wxhR + zb) = make_uint2(pack2(accr[mt][nt][0], accr[mt][nt][1]),
                                              pack2(accr[mt][nt][2], accr[mt][nt][3]));
            *(uint2*)(wxhI + zb) = make_uint2(pack2(acci[mt][nt][0], acci[mt][nt][1]),
                                              pack2(acci[mt][nt][2], acci[mt][nt][3]));
        }
}

// ---------------- pass I: complex ifft along i -> G[j][r][ob] (coalesced stores) ----------------
template<int RH>
__device__ __forceinline__ void ifft_i_body(const unsigned short* __restrict__ YR,
                                            const unsigned short* __restrict__ YI,
                                            float2* __restrict__ G, int j, int ob)
{
    float2 Gacc[16];
#pragma unroll
    for (int rr = 0; rr < 16; rr++) Gacc[rr] = make_float2(0.f, 0.f);
#pragma unroll
    for (int i = 0; i < 32; i++) {
        size_t yi_ = (size_t)(i * 17 + j) * 8192 + ob;
        float Yx = bf2f(YR[yi_]);
        float Yy = bf2f(YI[yi_]);
#pragma unroll
        for (int rr = 0; rr < 16; rr++) {
            int m = (i * (RH * 16 + rr)) & 31;     // compile-time constant
            Gacc[rr].x += Yx*COS32[m] - Yy*SIN32[m];
            Gacc[rr].y += Yx*SIN32[m] + Yy*COS32[m];
        }
    }
#pragma unroll
    for (int rr = 0; rr < 16; rr++) {
        G[((size_t)(j*32 + RH*16 + rr))*8192 + ob] =
            make_float2(Gacc[rr].x * (1.f/32.f), Gacc[rr].y * (1.f/32.f));
    }
}

__global__ __launch_bounds__(256) void ifft_i(const unsigned short* __restrict__ YR,
                                              const unsigned short* __restrict__ YI,
                                              float2* __restrict__ G) {
    int bid = blockIdx.x;
    int j   = bid >> 6;          // 0..16
    int rh  = (bid >> 5) & 1;    // 0..1
    int obc = bid & 31;          // 0..31
    int ob  = obc * 256 + threadIdx.x;
    if (rh == 0) ifft_i_body<0>(YR, YI, G, j, ob);
    else         ifft_i_body<1>(YR, YI, G, j, ob);
}

// ---------------- pass II: irfft along j + bias -> out[b][o][r][s] ----------------
// ob = b*256 + o (plane layout [f][b][o])
__global__ __launch_bounds__(256) void irfft_j(const float2* __restrict__ G,
                                               const float* __restrict__ bias,
                                               float* __restrict__ out) {
    int gid = blockIdx.x * 256 + threadIdx.x;
    int r = gid >> 13, ob = gid & 8191;
    int b = ob >> 8, o = ob & 255;
    float2 Gv[17];
#pragma unroll
    for (int jj = 0; jj < 17; jj++)
        Gv[jj] = G[((size_t)(jj*32 + r))*8192 + ob];
    float y[32];
    float g0 = Gv[0].x, g16 = Gv[16].x;
#pragma unroll
    for (int s = 0; s < 32; s++) y[s] = g0 + ((s & 1) ? -g16 : g16);
#pragma unroll
    for (int jj = 1; jj < 16; jj++) {
#pragma unroll
        for (int s = 0; s < 32; s++) {
            int m = (jj * s) & 31;                 // compile-time constant
            y[s] += 2.f * (Gv[jj].x * COS32[m] - Gv[jj].y * SIN32[m]);
        }
    }
    float bv = bias[o];
    float* op = out + ((size_t)(b * NCH + o) * 32 + r) * 32;
#pragma unroll
    for (int s = 0; s < 32; s++) op[s] = y[s] * (1.f/32.f) + bv;
}

extern "C" void kernel_launch(void* const* d_in, const int* in_sizes, int n_in,
                              void* d_out, int out_size, void* d_ws, size_t ws_size,
                              hipStream_t stream) {
    (void)in_sizes; (void)n_in; (void)out_size;
    if (ws_size < WS_NEED) return;

    const float* x     = (const float*)d_in[0];
    const float* w     = (const float*)d_in[1];
    const float* alpha = (const float*)d_in[2];
    const float* H     = (const float*)d_in[3];
    const float* bias  = (const float*)d_in[4];
    float* out = (float*)d_out;

    char* ws = (char*)d_ws;
    unsigned short* Afrag = (unsigned short*)(ws + OFF_AFRAG);
    float2* tmp = (float2*)(ws + OFF_AFRAG);   // dead before a_build writes Afrag
    float2* G   = (float2*)(ws + OFF_AFRAG);   // live after neum passes (Afrag dead)
    unsigned short* tbr  = (unsigned short*)(ws + OFF_TBR);
    unsigned short* tbi  = (unsigned short*)(ws + OFF_TBI);
    float* z32r = (float*)(ws + OFF_Z32R);
    float* z32i = (float*)(ws + OFF_Z32I);
    unsigned short* wxhR = (unsigned short*)(ws + OFF_WXHR);
    unsigned short* wxhI = (unsigned short*)(ws + OFF_WXHI);
    unsigned short* Hfrag = (unsigned short*)(ws + OFF_HFRAG);
    float* red = (float*)(ws + OFF_RED);
    float* sig = red + 256;

    norm_part<<<256, 256, 0, stream>>>(w, red);
    norm_final<<<1, 256, 0, stream>>>(red, alpha, sig);
    hfrag_build<<<dim3(8, 16), 64, 0, stream>>>(H, Hfrag);

    rfft2_reg<<<1024, 256, 0, stream>>>(x, tmp);
    transpose_z<<<dim3(8, 17, 32), 256, 0, stream>>>(tmp, z32r, z32i);

    a_build_frag<<<dim3(16, 8, 8), 256, 0, stream>>>(w, sig, Afrag);
    neum1<<<NF*2, 256, 0, stream>>>(Afrag, z32r, z32i, tbr, tbi);
    neum2h<<<NF, 512, 0, stream>>>(Afrag, Hfrag, tbr, tbi, z32r, z32i, wxhR, wxhI);

    ifft_i<<<1088, 256, 0, stream>>>(wxhR, wxhI, G);
    irfft_j<<<1024, 256, 0, stream>>>(G, bias, out);
}

// Round 10
// 246.332 us; speedup vs baseline: 1.6958x; 1.6958x over previous
//
#include <hip/hip_runtime.h>
#include <cstddef>

#define PI_F 3.14159265358979323846f

#define NCH 256   // C
#define NB  32    // B
#define NF  544   // n*(n/2+1),  f = i*17 + j

typedef short  bf16x8 __attribute__((ext_vector_type(8)));
typedef float  f32x4  __attribute__((ext_vector_type(4)));

// ---- workspace layout (bytes), single-chunk ----
// Afrag hosts: tmp (rfft2 out, dead before a_build) and G (after neum passes).
#define SZ_AFRAG ((size_t)NF*8*16*2*1024)       // 142,606,336
#define SZ_PBH   ((size_t)NF*NB*NCH*2)          // 8,912,896   (bf16 plane)
#define SZ_P32H  ((size_t)NF*NB*NCH*4)          // 17,825,792  (fp32 plane)
#define OFF_AFRAG ((size_t)0)
#define OFF_TBR  (OFF_AFRAG + SZ_AFRAG)
#define OFF_TBI  (OFF_TBR + SZ_PBH)
#define OFF_Z32R (OFF_TBI + SZ_PBH)
#define OFF_Z32I (OFF_Z32R + SZ_P32H)
#define OFF_WXHR (OFF_Z32I + SZ_P32H)
#define OFF_WXHI (OFF_WXHR + SZ_PBH)
#define OFF_HFRAG (OFF_WXHI + SZ_PBH)
#define SZ_HFRAG ((size_t)8*16*1024)            // 131,072
#define OFF_RED  (OFF_HFRAG + SZ_HFRAG)
#define WS_NEED  (OFF_RED + (size_t)4096)       // 214,044,672 <= 214,175,744 proven in R1

// 32-point twiddle tables: COS32[k]=cos(2pi k/32), SIN32[k]=sin(2pi k/32)
__device__ constexpr float COS32[32] = {
     1.0000000000f,  0.9807852804f,  0.9238795325f,  0.8314696123f,
     0.7071067812f,  0.5555702330f,  0.3826834324f,  0.1950903220f,
     0.0000000000f, -0.1950903220f, -0.3826834324f, -0.5555702330f,
    -0.7071067812f, -0.8314696123f, -0.9238795325f, -0.9807852804f,
    -1.0000000000f, -0.9807852804f, -0.9238795325f, -0.8314696123f,
    -0.7071067812f, -0.5555702330f, -0.3826834324f, -0.1950903220f,
    -0.0000000000f,  0.1950903220f,  0.3826834324f,  0.5555702330f,
     0.7071067812f,  0.8314696123f,  0.9238795325f,  0.9807852804f };
__device__ constexpr float SIN32[32] = {
     0.0000000000f,  0.1950903220f,  0.3826834324f,  0.5555702330f,
     0.7071067812f,  0.8314696123f,  0.9238795325f,  0.9807852804f,
     1.0000000000f,  0.9807852804f,  0.9238795325f,  0.8314696123f,
     0.7071067812f,  0.5555702330f,  0.3826834324f,  0.1950903220f,
     0.0000000000f, -0.1950903220f, -0.3826834324f, -0.5555702330f,
    -0.7071067812f, -0.8314696123f, -0.9238795325f, -0.9807852804f,
    -1.0000000000f, -0.9807852804f, -0.9238795325f, -0.8314696123f,
    -0.7071067812f, -0.5555702330f, -0.3826834324f, -0.1950903220f };

__device__ __forceinline__ unsigned short f2bf(float x) {
    unsigned int u = __float_as_uint(x);
    u += 0x7FFFu + ((u >> 16) & 1u);            // RNE
    return (unsigned short)(u >> 16);
}
__device__ __forceinline__ float bf2f(unsigned int h) {
    return __uint_as_float(h << 16);
}
__device__ __forceinline__ unsigned int pack2(float a, float b) {
    return (unsigned int)f2bf(a) | ((unsigned int)f2bf(b) << 16);
}

// ---------------- norm of wfft (closed form via Parseval) ----------------
__global__ void norm_part(const float* __restrict__ w, float* __restrict__ red) {
    int idx = blockIdx.x * 256 + threadIdx.x;
    const float* wp = w + (size_t)idx * 9;
    float s2 = 0.f, aa = 0.f, bb = 0.f;
#pragma unroll
    for (int u = 0; u < 3; u++) {
        float w0 = wp[u*3+0], w1 = wp[u*3+1], w2 = wp[u*3+2];
        s2 += w0*w0 + w1*w1 + w2*w2;
        float au = w0 + w1 + w2, bu = w0 - w1 + w2;
        aa += au*au; bb += bu*bu;
    }
    float p = 512.f*s2 + 16.f*(aa + bb);
    __shared__ float sm[256];
    sm[threadIdx.x] = p; __syncthreads();
    for (int s = 128; s > 0; s >>= 1) {
        if (threadIdx.x < s) sm[threadIdx.x] += sm[threadIdx.x + s];
        __syncthreads();
    }
    if (threadIdx.x == 0) red[blockIdx.x] = sm[0];
}

__global__ void norm_final(const float* __restrict__ red, const float* __restrict__ alpha,
                           float* __restrict__ sig) {
    __shared__ float sm[256];
    sm[threadIdx.x] = red[threadIdx.x]; __syncthreads();
    for (int s = 128; s > 0; s >>= 1) {
        if (threadIdx.x < s) sm[threadIdx.x] += sm[threadIdx.x + s];
        __syncthreads();
    }
    if (threadIdx.x == 0) sig[0] = alpha[0] / sqrtf(sm[0]);
}

// ---------------- H fragments (A-operand: m=o, k=c) ----------------
__global__ void hfrag_build(const float* __restrict__ H, unsigned short* __restrict__ Hfrag) {
    int kk = blockIdx.x, mt = blockIdx.y, lane = threadIdx.x;   // 64 threads
    int o = mt*16 + (lane & 15), c0 = kk*32 + (lane >> 4)*8;
    const float* hp = H + (size_t)o*NCH + c0;
    uint4 u;
    u.x = pack2(hp[0], hp[1]); u.y = pack2(hp[2], hp[3]);
    u.z = pack2(hp[4], hp[5]); u.w = pack2(hp[6], hp[7]);
    ((uint4*)Hfrag)[((size_t)kk*16 + mt)*64 + lane] = u;
}

// ---------------- rfft2: register-resident DFT, 8 tiles per 256-thread block ----------------
// NOTE: no min-waves arg — __launch_bounds__(256,4) forced VGPR 64 and spilled
// (R9: 700 MB scratch traffic, 4x slower). Compiler's 136 VGPR is correct here.
__global__ __launch_bounds__(256) void rfft2_reg(const float* __restrict__ x,
                                                 float2* __restrict__ tmp)
{
    __shared__ float2 T[8][544];       // [half][r*17+j], ~35 KB
    __shared__ float wc[32], wsn[32];
    int t = threadIdx.x;
    int half = t >> 5, lane = t & 31;
    int cb = blockIdx.x * 8 + half;    // tile index in tmp order: cb = c*32 + b
    int c = cb >> 5, b = cb & 31;
    if (t < 32) { wc[t] = COS32[t]; wsn[t] = SIN32[t]; }
    float xr[32];
    const float* xp = x + ((size_t)(b * NCH + c)) * 1024 + lane * 32;
#pragma unroll
    for (int q = 0; q < 8; q++) {
        float4 v = *(const float4*)(xp + q*4);
        xr[q*4+0] = v.x; xr[q*4+1] = v.y; xr[q*4+2] = v.z; xr[q*4+3] = v.w;
    }
    // step 1: T[r=lane][j] = sum_s x[r,s] e^{-2pi i j s/32}   (constant twiddles)
#pragma unroll
    for (int j = 0; j < 17; j++) {
        float ax = 0.f, ay = 0.f;
#pragma unroll
        for (int s = 0; s < 32; s++) {
            int m = (j * s) & 31;
            ax += xr[s] * COS32[m];
            ay -= xr[s] * SIN32[m];
        }
        T[half][lane*17 + j] = make_float2(ax, ay);
    }
    __syncthreads();
    float wr_[16], wi_[16];
#pragma unroll
    for (int r = 0; r < 16; r++) {
        int m = (lane * r) & 31;
        wr_[r] = wc[m]; wi_[r] = wsn[m];
    }
    float sgn = (lane & 1) ? -1.f : 1.f;    // (-1)^i
    // step 2: z[i=lane][j] = sum_{r<16} e^{-2pi i i r/32} (T[r][j] + (-1)^i T[r+16][j])
    float2* op = tmp + (size_t)cb * 544 + lane * 17;
#pragma unroll
    for (int j = 0; j < 17; j++) {
        float ax = 0.f, ay = 0.f;
#pragma unroll
        for (int r = 0; r < 16; r++) {
            float2 t1 = T[half][r*17 + j];
            float2 t2 = T[half][(r+16)*17 + j];
            float ex = fmaf(sgn, t2.x, t1.x);
            float ey = fmaf(sgn, t2.y, t1.y);
            ax += ex * wr_[r] + ey * wi_[r];
            ay += ey * wr_[r] - ex * wi_[r];
        }
        op[j] = make_float2(ax, ay);
    }
}

// ---------------- transpose tmp[cb][f] -> fp32 planes [f][b][c] ----------------
__global__ __launch_bounds__(256) void transpose_z(const float2* __restrict__ tmp,
        float* __restrict__ z32r, float* __restrict__ z32i)
{
    __shared__ float2 tile[32][33];
    int ct = blockIdx.x, ft = blockIdx.y, b = blockIdx.z;
    int t = threadIdx.x;
#pragma unroll
    for (int it = 0; it < 4; it++) {
        int idx = t + it*256; int cl = idx >> 5, fl = idx & 31;
        tile[cl][fl] = tmp[((size_t)((ct*32 + cl)*32 + b))*544 + ft*32 + fl];
    }
    __syncthreads();
#pragma unroll
    for (int it = 0; it < 4; it++) {
        int idx = t + it*256; int fl = idx >> 5, cl = idx & 31;
        float2 v = tile[cl][fl];
        size_t zi_ = ((size_t)(ft*32 + fl)*NB + b)*NCH + ct*32 + cl;
        z32r[zi_] = v.x; z32i[zi_] = v.y;
    }
}

// ---------------- A-build into MFMA fragment order (table-lookup form) ----------------
__global__ __launch_bounds__(256) void a_build_frag(const float* __restrict__ w,
        const float* __restrict__ sig, unsigned short* __restrict__ Afrag)
{
    __shared__ float2 wtab[32];
    __shared__ unsigned short lar[512], lai[512];
    int t = threadIdx.x;
    if (t < 32) {
        float ph = -2.f * PI_F * (float)t / 32.f;
        wtab[t] = make_float2(cosf(ph), sinf(ph));
    }
    int mt = blockIdx.x, kk = blockIdx.y, fs = blockIdx.z;
    int c = mt*16 + (t & 15), cpl = t >> 4;
    int cpA = kk*32 + cpl, cpB = cpA + 16;
    float ua[9], va[9], ub[9], vb[9];
    {
        const float* pa1 = w + ((size_t)c*NCH + cpA)*9;
        const float* pb1 = w + ((size_t)c*NCH + cpB)*9;
        const float* pa2 = w + ((size_t)cpA*NCH + c)*9;
        const float* pb2 = w + ((size_t)cpB*NCH + c)*9;
#pragma unroll
        for (int q = 0; q < 9; q++) {
            float w1a = pa1[q], w2a = pa2[q], w1b = pb1[q], w2b = pb2[q];
            ua[q] = w1a - w2a; va[q] = w1a + w2a;
            ub[q] = w1b - w2b; vb[q] = w1b + w2b;
        }
    }
    float s = sig[0];
    int la_ = ((c & 15) + 16*(cpl>>3))*8 + (cpl & 7);
    int lb_ = la_ + 32*8;
    __syncthreads();
    for (int fl = fs*68; fl < fs*68 + 68; fl++) {
        int i = fl / 17, jj = fl - i * 17;    // f = i*17 + j ordering
        int m_[9];
        m_[0] = (i + jj) & 31;  m_[1] = i;             m_[2] = (i - jj) & 31;
        m_[3] = jj;             m_[4] = 0;             m_[5] = (32 - jj) & 31;
        m_[6] = (jj - i) & 31;  m_[7] = (32 - i) & 31; m_[8] = (64 - i - jj) & 31;
        float ArA = 0.f, AiA = 0.f, ArB = 0.f, AiB = 0.f;
#pragma unroll
        for (int q = 0; q < 9; q++) {
            float2 P = wtab[m_[q]];
            ArA += ua[q] * P.x; AiA += va[q] * P.y;
            ArB += ub[q] * P.x; AiB += vb[q] * P.y;
        }
        lar[la_] = f2bf(s*ArA); lai[la_] = f2bf(s*AiA);
        lar[lb_] = f2bf(s*ArB); lai[lb_] = f2bf(s*AiB);
        __syncthreads();
        size_t bch = (((size_t)fl*8 + kk)*16 + mt)*256;   // uint2 units
        ((uint2*)Afrag)[bch + t] = (t < 128) ? ((const uint2*)lar)[t]
                                             : ((const uint2*)lai)[t - 128];
        __syncthreads();
    }
}

// ---------------- neum1: t = z - A z  (z staged from fp32, identity from bf16 LDS) ----------------
__global__ __launch_bounds__(256) void neum1(
    const unsigned short* __restrict__ Afrag,
    const float* __restrict__ z32r, const float* __restrict__ z32i,
    unsigned short* __restrict__ outR, unsigned short* __restrict__ outI)
{
    __shared__ uint4 lz[2][1024];   // 32 KB, swizzled bf16
    int fl = blockIdx.x >> 1, half = blockIdx.x & 1;
    int f = fl;
    int t = threadIdx.x;
    const float4* s0 = (const float4*)(z32r + (size_t)f*8192);
    const float4* s1 = (const float4*)(z32i + (size_t)f*8192);
    for (int u = t; u < 1024; u += 256) {
        int b = u >> 5, o16 = u & 31;
        int du = b*32 + (o16 ^ (b & 7));
        float4 va = s0[u*2], vb = s0[u*2+1];
        lz[0][du] = make_uint4(pack2(va.x,va.y), pack2(va.z,va.w),
                               pack2(vb.x,vb.y), pack2(vb.z,vb.w));
        float4 vc = s1[u*2], vd = s1[u*2+1];
        lz[1][du] = make_uint4(pack2(vc.x,vc.y), pack2(vc.z,vc.w),
                               pack2(vd.x,vd.y), pack2(vd.z,vd.w));
    }
    __syncthreads();
    int w = t >> 6, lane = t & 63, lo = lane & 15, hi = lane >> 4;
    f32x4 accr[2][2], acci[2][2];
    f32x4 zz = {0.f, 0.f, 0.f, 0.f};
#pragma unroll
    for (int mt = 0; mt < 2; mt++)
#pragma unroll
        for (int nt = 0; nt < 2; nt++) { accr[mt][nt] = zz; acci[mt][nt] = zz; }
    const uint4* A4 = (const uint4*)Afrag;
    for (int kk = 0; kk < 8; kk++) {
        bf16x8 ar[2], ai[2], ain[2];
#pragma unroll
        for (int mt = 0; mt < 2; mt++) {
            int mtg = half*8 + w*2 + mt;
            size_t idx = ((((size_t)fl*8 + kk)*16 + mtg)*2)*64 + lane;
            uint4 va = A4[idx], vb = A4[idx + 64];
            ar[mt] = __builtin_bit_cast(bf16x8, va);
            ai[mt] = __builtin_bit_cast(bf16x8, vb);
            uint4 vn = make_uint4(vb.x ^ 0x80008000u, vb.y ^ 0x80008000u,
                                  vb.z ^ 0x80008000u, vb.w ^ 0x80008000u);
            ain[mt] = __builtin_bit_cast(bf16x8, vn);
        }
        bf16x8 zr[2], zi_[2];
#pragma unroll
        for (int nt = 0; nt < 2; nt++) {
            int b = nt*16 + lo;
            int du = b*32 + ((kk*4 + hi) ^ (b & 7));
            zr[nt]  = __builtin_bit_cast(bf16x8, lz[0][du]);
            zi_[nt] = __builtin_bit_cast(bf16x8, lz[1][du]);
        }
#pragma unroll
        for (int mt = 0; mt < 2; mt++)
#pragma unroll
            for (int nt = 0; nt < 2; nt++) {
                accr[mt][nt] = __builtin_amdgcn_mfma_f32_16x16x32_bf16(ar[mt],  zr[nt],  accr[mt][nt], 0, 0, 0);
                accr[mt][nt] = __builtin_amdgcn_mfma_f32_16x16x32_bf16(ain[mt], zi_[nt], accr[mt][nt], 0, 0, 0);
                acci[mt][nt] = __builtin_amdgcn_mfma_f32_16x16x32_bf16(ar[mt],  zi_[nt], acci[mt][nt], 0, 0, 0);
                acci[mt][nt] = __builtin_amdgcn_mfma_f32_16x16x32_bf16(ai[mt],  zr[nt],  acci[mt][nt], 0, 0, 0);
            }
    }
#pragma unroll
    for (int mt = 0; mt < 2; mt++)
#pragma unroll
        for (int nt = 0; nt < 2; nt++) {
            int c0 = half*128 + w*32 + mt*16 + hi*4;
            int b  = nt*16 + lo;
            int o16c = c0 >> 3;
            int duc = b*32 + (o16c ^ (b & 7));
            int sel = (c0 >> 2) & 1;
            uint2 pzr = ((const uint2*)&lz[0][duc])[sel];
            uint2 pzi = ((const uint2*)&lz[1][duc])[sel];
            float zfr[4] = { bf2f(pzr.x & 0xffffu), bf2f(pzr.x >> 16),
                             bf2f(pzr.y & 0xffffu), bf2f(pzr.y >> 16) };
            float zfi[4] = { bf2f(pzi.x & 0xffffu), bf2f(pzi.x >> 16),
                             bf2f(pzi.y & 0xffffu), bf2f(pzi.y >> 16) };
            size_t zb = ((size_t)f*NB + b)*NCH + c0;
            float vr[4], vi[4];
#pragma unroll
            for (int jj = 0; jj < 4; jj++) {
                vr[jj] = zfr[jj] - accr[mt][nt][jj];
                vi[jj] = zfi[jj] - acci[mt][nt][jj];
            }
            *(uint2*)(outR + zb) = make_uint2(pack2(vr[0], vr[1]), pack2(vr[2], vr[3]));
            *(uint2*)(outI + zb) = make_uint2(pack2(vi[0], vi[1]), pack2(vi[2], vi[3]));
        }
}

// ---------------- neum2h: wx = z32 - 2 A t  ->  wxh = H wx  (fused, full f per block) ----------------
__global__ __launch_bounds__(512) void neum2h(
    const unsigned short* __restrict__ Afrag,
    const unsigned short* __restrict__ Hfrag,
    const unsigned short* __restrict__ TR, const unsigned short* __restrict__ TI,
    const float* __restrict__ z32r, const float* __restrict__ z32i,
    unsigned short* __restrict__ wxhR, unsigned short* __restrict__ wxhI)
{
    __shared__ uint4 lz[2][1024];   // 32 KB: stages t, then reused for wx
    int fl = blockIdx.x;
    int f = fl;
    int t = threadIdx.x;
    const uint4* s0 = (const uint4*)(TR + (size_t)f*8192);
    const uint4* s1 = (const uint4*)(TI + (size_t)f*8192);
    for (int u = t; u < 2048; u += 512) {
        int p = u >> 10, idx = u & 1023;
        int b = idx >> 5, o16 = idx & 31;
        lz[p][b*32 + (o16 ^ (b & 7))] = (p ? s1 : s0)[idx];
    }
    __syncthreads();
    int w = t >> 6, lane = t & 63, lo = lane & 15, hi = lane >> 4;
    const uint4* A4 = (const uint4*)Afrag;
    const uint4* H4 = (const uint4*)Hfrag;
    f32x4 accr[2][2], acci[2][2];
    f32x4 zz = {0.f, 0.f, 0.f, 0.f};
#pragma unroll
    for (int mt = 0; mt < 2; mt++)
#pragma unroll
        for (int nt = 0; nt < 2; nt++) { accr[mt][nt] = zz; acci[mt][nt] = zz; }
    // ---- matmul 1: acc = A * t ----
    for (int kk = 0; kk < 8; kk++) {
        bf16x8 ar[2], ai[2], ain[2];
#pragma unroll
        for (int mt = 0; mt < 2; mt++) {
            int mtg = w*2 + mt;
            size_t idx = ((((size_t)fl*8 + kk)*16 + mtg)*2)*64 + lane;
            uint4 va = A4[idx], vb = A4[idx + 64];
            ar[mt] = __builtin_bit_cast(bf16x8, va);
            ai[mt] = __builtin_bit_cast(bf16x8, vb);
            uint4 vn = make_uint4(vb.x ^ 0x80008000u, vb.y ^ 0x80008000u,
                                  vb.z ^ 0x80008000u, vb.w ^ 0x80008000u);
            ain[mt] = __builtin_bit_cast(bf16x8, vn);
        }
        bf16x8 zr[2], zi_[2];
#pragma unroll
        for (int nt = 0; nt < 2; nt++) {
            int b = nt*16 + lo;
            int du = b*32 + ((kk*4 + hi) ^ (b & 7));
            zr[nt]  = __builtin_bit_cast(bf16x8, lz[0][du]);
            zi_[nt] = __builtin_bit_cast(bf16x8, lz[1][du]);
        }
#pragma unroll
        for (int mt = 0; mt < 2; mt++)
#pragma unroll
            for (int nt = 0; nt < 2; nt++) {
                accr[mt][nt] = __builtin_amdgcn_mfma_f32_16x16x32_bf16(ar[mt],  zr[nt],  accr[mt][nt], 0, 0, 0);
                accr[mt][nt] = __builtin_amdgcn_mfma_f32_16x16x32_bf16(ain[mt], zi_[nt], accr[mt][nt], 0, 0, 0);
                acci[mt][nt] = __builtin_amdgcn_mfma_f32_16x16x32_bf16(ar[mt],  zi_[nt], acci[mt][nt], 0, 0, 0);
                acci[mt][nt] = __builtin_amdgcn_mfma_f32_16x16x32_bf16(ai[mt],  zr[nt],  acci[mt][nt], 0, 0, 0);
            }
    }
    __syncthreads();   // all waves done reading t from LDS
    // ---- epilogue 1: wx = z32 - 2 acc; write bf16 wx into LDS ----
#pragma unroll
    for (int mt = 0; mt < 2; mt++)
#pragma unroll
        for (int nt = 0; nt < 2; nt++) {
            int c0 = w*32 + mt*16 + hi*4;
            int b  = nt*16 + lo;
            size_t zb = ((size_t)f*NB + b)*NCH + c0;
            float4 z4r = *(const float4*)(z32r + zb);
            float4 z4i = *(const float4*)(z32i + zb);
            float vr[4] = { z4r.x - 2.f*accr[mt][nt][0], z4r.y - 2.f*accr[mt][nt][1],
                            z4r.z - 2.f*accr[mt][nt][2], z4r.w - 2.f*accr[mt][nt][3] };
            float vi[4] = { z4i.x - 2.f*acci[mt][nt][0], z4i.y - 2.f*acci[mt][nt][1],
                            z4i.z - 2.f*acci[mt][nt][2], z4i.w - 2.f*acci[mt][nt][3] };
            int o16c = c0 >> 3;
            int duc = b*32 + (o16c ^ (b & 7));
            int sel = (c0 >> 2) & 1;
            ((uint2*)&lz[0][duc])[sel] = make_uint2(pack2(vr[0], vr[1]), pack2(vr[2], vr[3]));
            ((uint2*)&lz[1][duc])[sel] = make_uint2(pack2(vi[0], vi[1]), pack2(vi[2], vi[3]));
        }
    __syncthreads();
    // ---- matmul 2: wxh = H * wx ----
#pragma unroll
    for (int mt = 0; mt < 2; mt++)
#pragma unroll
        for (int nt = 0; nt < 2; nt++) { accr[mt][nt] = zz; acci[mt][nt] = zz; }
    for (int kk = 0; kk < 8; kk++) {
        bf16x8 hm[2];
#pragma unroll
        for (int mt = 0; mt < 2; mt++) {
            int mtg = w*2 + mt;
            hm[mt] = __builtin_bit_cast(bf16x8, H4[((size_t)kk*16 + mtg)*64 + lane]);
        }
        bf16x8 zr[2], zi_[2];
#pragma unroll
        for (int nt = 0; nt < 2; nt++) {
            int b = nt*16 + lo;
            int du = b*32 + ((kk*4 + hi) ^ (b & 7));
            zr[nt]  = __builtin_bit_cast(bf16x8, lz[0][du]);
            zi_[nt] = __builtin_bit_cast(bf16x8, lz[1][du]);
        }
#pragma unroll
        for (int mt = 0; mt < 2; mt++)
#pragma unroll
            for (int nt = 0; nt < 2; nt++) {
                accr[mt][nt] = __builtin_amdgcn_mfma_f32_16x16x32_bf16(hm[mt], zr[nt],  accr[mt][nt], 0, 0, 0);
                acci[mt][nt] = __builtin_amdgcn_mfma_f32_16x16x32_bf16(hm[mt], zi_[nt], acci[mt][nt], 0, 0, 0);
            }
    }
    // ---- epilogue 2: wxh bf16 planes, [f][b][o] layout ----
#pragma unroll
    for (int mt = 0; mt < 2; mt++)
#pragma unroll
        for (int nt = 0; nt < 2; nt++) {
            int o0 = w*32 + mt*16 + hi*4;
            int b  = nt*16 + lo;
            size_t zb = ((size_t)f*NB + b)*NCH + o0;
            *(uint2*)(wxhR + zb) = make_uint2(pack2(accr[mt][nt][0], accr[mt][nt][1]),
                                              pack2(accr[mt][nt][2], accr[mt][nt][3]));
            *(uint2*)(wxhI + zb) = make_uint2(pack2(acci[mt][nt][0], acci[mt][nt][1]),
                                              pack2(acci[mt][nt][2], acci[mt][nt][3]));
        }
}

// ---------------- pass I: complex ifft along i -> G[j][r][ob] (coalesced stores) ----------------
template<int RH>
__device__ __forceinline__ void ifft_i_body(const unsigned short* __restrict__ YR,
                                            const unsigned short* __restrict__ YI,
                                            float2* __restrict__ G, int j, int ob)
{
    float2 Gacc[16];
#pragma unroll
    for (int rr = 0; rr < 16; rr++) Gacc[rr] = make_float2(0.f, 0.f);
#pragma unroll
    for (int i = 0; i < 32; i++) {
        size_t yi_ = (size_t)(i * 17 + j) * 8192 + ob;
        float Yx = bf2f(YR[yi_]);
        float Yy = bf2f(YI[yi_]);
#pragma unroll
        for (int rr = 0; rr < 16; rr++) {
            int m = (i * (RH * 16 + rr)) & 31;     // compile-time constant
            Gacc[rr].x += Yx*COS32[m] - Yy*SIN32[m];
            Gacc[rr].y += Yx*SIN32[m] + Yy*COS32[m];
        }
    }
#pragma unroll
    for (int rr = 0; rr < 16; rr++) {
        G[((size_t)(j*32 + RH*16 + rr))*8192 + ob] =
            make_float2(Gacc[rr].x * (1.f/32.f), Gacc[rr].y * (1.f/32.f));
    }
}

__global__ __launch_bounds__(256) void ifft_i(const unsigned short* __restrict__ YR,
                                              const unsigned short* __restrict__ YI,
                                              float2* __restrict__ G) {
    int bid = blockIdx.x;
    int j   = bid >> 6;          // 0..16
    int rh  = (bid >> 5) & 1;    // 0..1
    int obc = bid & 31;          // 0..31
    int ob  = obc * 256 + threadIdx.x;
    if (rh == 0) ifft_i_body<0>(YR, YI, G, j, ob);
    else         ifft_i_body<1>(YR, YI, G, j, ob);
}

// ---------------- pass II: irfft along j + bias -> out[b][o][r][s] ----------------
// ob = b*256 + o (plane layout [f][b][o])
__global__ __launch_bounds__(256) void irfft_j(const float2* __restrict__ G,
                                               const float* __restrict__ bias,
                                               float* __restrict__ out) {
    int gid = blockIdx.x * 256 + threadIdx.x;
    int r = gid >> 13, ob = gid & 8191;
    int b = ob >> 8, o = ob & 255;
    float2 Gv[17];
#pragma unroll
    for (int jj = 0; jj < 17; jj++)
        Gv[jj] = G[((size_t)(jj*32 + r))*8192 + ob];
    float y[32];
    float g0 = Gv[0].x, g16 = Gv[16].x;
#pragma unroll
    for (int s = 0; s < 32; s++) y[s] = g0 + ((s & 1) ? -g16 : g16);
#pragma unroll
    for (int jj = 1; jj < 16; jj++) {
#pragma unroll
        for (int s = 0; s < 32; s++) {
            int m = (jj * s) & 31;                 // compile-time constant
            y[s] += 2.f * (Gv[jj].x * COS32[m] - Gv[jj].y * SIN32[m]);
        }
    }
    float bv = bias[o];
    float* op = out + ((size_t)(b * NCH + o) * 32 + r) * 32;
#pragma unroll
    for (int s = 0; s < 32; s++) op[s] = y[s] * (1.f/32.f) + bv;
}

extern "C" void kernel_launch(void* const* d_in, const int* in_sizes, int n_in,
                              void* d_out, int out_size, void* d_ws, size_t ws_size,
                              hipStream_t stream) {
    (void)in_sizes; (void)n_in; (void)out_size;
    if (ws_size < WS_NEED) return;

    const float* x     = (const float*)d_in[0];
    const float* w     = (const float*)d_in[1];
    const float* alpha = (const float*)d_in[2];
    const float* H     = (const float*)d_in[3];
    const float* bias  = (const float*)d_in[4];
    float* out = (float*)d_out;

    char* ws = (char*)d_ws;
    unsigned short* Afrag = (unsigned short*)(ws + OFF_AFRAG);
    float2* tmp = (float2*)(ws + OFF_AFRAG);   // dead before a_build writes Afrag
    float2* G   = (float2*)(ws + OFF_AFRAG);   // live after neum passes (Afrag dead)
    unsigned short* tbr  = (unsigned short*)(ws + OFF_TBR);
    unsigned short* tbi  = (unsigned short*)(ws + OFF_TBI);
    float* z32r = (float*)(ws + OFF_Z32R);
    float* z32i = (float*)(ws + OFF_Z32I);
    unsigned short* wxhR = (unsigned short*)(ws + OFF_WXHR);
    unsigned short* wxhI = (unsigned short*)(ws + OFF_WXHI);
    unsigned short* Hfrag = (unsigned short*)(ws + OFF_HFRAG);
    float* red = (float*)(ws + OFF_RED);
    float* sig = red + 256;

    norm_part<<<256, 256, 0, stream>>>(w, red);
    norm_final<<<1, 256, 0, stream>>>(red, alpha, sig);
    hfrag_build<<<dim3(8, 16), 64, 0, stream>>>(H, Hfrag);

    rfft2_reg<<<1024, 256, 0, stream>>>(x, tmp);
    transpose_z<<<dim3(8, 17, 32), 256, 0, stream>>>(tmp, z32r, z32i);

    a_build_frag<<<dim3(16, 8, 8), 256, 0, stream>>>(w, sig, Afrag);
    neum1<<<NF*2, 256, 0, stream>>>(Afrag, z32r, z32i, tbr, tbi);
    neum2h<<<NF, 512, 0, stream>>>(Afrag, Hfrag, tbr, tbi, z32r, z32i, wxhR, wxhI);

    ifft_i<<<1088, 256, 0, stream>>>(wxhR, wxhI, G);
    irfft_j<<<1024, 256, 0, stream>>>(G, bias, out);
}

// Round 11
// 218.220 us; speedup vs baseline: 1.9142x; 1.1288x over previous
//
#include <hip/hip_runtime.h>
#include <hip/hip_fp8.h>
#include <cstddef>

#define PI_F 3.14159265358979323846f

#define NCH 256   // C
#define NB  32    // B
#define NF  544   // n*(n/2+1),  f = i*17 + j

#define ASCALE     65536.0f
#define INV_ASCALE (1.0f/65536.0f)

typedef short  bf16x8 __attribute__((ext_vector_type(8)));
typedef float  f32x4  __attribute__((ext_vector_type(4)));

// ---- workspace layout (bytes), single-chunk, fp8 A ----
#define SZ_AFRAG ((size_t)NF*8*16*1024)         // 71,303,168 (fp8 fragments; tmp & G alias)
#define SZ_P8    ((size_t)NF*NB*NCH)            // 4,456,448  (fp8 plane)
#define SZ_PB    ((size_t)NF*NB*NCH*2)          // 8,912,896  (bf16 plane)
#define SZ_P32   ((size_t)NF*NB*NCH*4)          // 17,825,792 (fp32 plane)
#define OFF_AFRAG ((size_t)0)
#define OFF_T8R  (OFF_AFRAG + SZ_AFRAG)
#define OFF_T8I  (OFF_T8R + SZ_P8)
#define OFF_Z8R  (OFF_T8I + SZ_P8)
#define OFF_Z8I  (OFF_Z8R + SZ_P8)
#define OFF_Z32R (OFF_Z8I + SZ_P8)
#define OFF_Z32I (OFF_Z32R + SZ_P32)
#define OFF_WXHR (OFF_Z32I + SZ_P32)
#define OFF_WXHI (OFF_WXHR + SZ_PB)
#define OFF_HFRAG (OFF_WXHI + SZ_PB)
#define SZ_HFRAG ((size_t)8*16*1024)            // 131,072
#define OFF_RED  (OFF_HFRAG + SZ_HFRAG)
#define WS_NEED  (OFF_RED + (size_t)4096)       // ~142.7 MB (well under proven 214 MB)

// 32-point twiddle tables: COS32[k]=cos(2pi k/32), SIN32[k]=sin(2pi k/32)
__device__ constexpr float COS32[32] = {
     1.0000000000f,  0.9807852804f,  0.9238795325f,  0.8314696123f,
     0.7071067812f,  0.5555702330f,  0.3826834324f,  0.1950903220f,
     0.0000000000f, -0.1950903220f, -0.3826834324f, -0.5555702330f,
    -0.7071067812f, -0.8314696123f, -0.9238795325f, -0.9807852804f,
    -1.0000000000f, -0.9807852804f, -0.9238795325f, -0.8314696123f,
    -0.7071067812f, -0.5555702330f, -0.3826834324f, -0.1950903220f,
    -0.0000000000f,  0.1950903220f,  0.3826834324f,  0.5555702330f,
     0.7071067812f,  0.8314696123f,  0.9238795325f,  0.9807852804f };
__device__ constexpr float SIN32[32] = {
     0.0000000000f,  0.1950903220f,  0.3826834324f,  0.5555702330f,
     0.7071067812f,  0.8314696123f,  0.9238795325f,  0.9807852804f,
     1.0000000000f,  0.9807852804f,  0.9238795325f,  0.8314696123f,
     0.7071067812f,  0.5555702330f,  0.3826834324f,  0.1950903220f,
     0.0000000000f, -0.1950903220f, -0.3826834324f, -0.5555702330f,
    -0.7071067812f, -0.8314696123f, -0.9238795325f, -0.9807852804f,
    -1.0000000000f, -0.9807852804f, -0.9238795325f, -0.8314696123f,
    -0.7071067812f, -0.5555702330f, -0.3826834324f, -0.1950903220f };

__device__ __forceinline__ unsigned short f2bf(float x) {
    unsigned int u = __float_as_uint(x);
    u += 0x7FFFu + ((u >> 16) & 1u);            // RNE
    return (unsigned short)(u >> 16);
}
__device__ __forceinline__ float bf2f(unsigned int h) {
    return __uint_as_float(h << 16);
}
__device__ __forceinline__ unsigned int pack2(float a, float b) {
    return (unsigned int)f2bf(a) | ((unsigned int)f2bf(b) << 16);
}
__device__ __forceinline__ unsigned char f2e4m3(float x) {
    __hip_fp8_e4m3 h(x);
    return (unsigned char)h.__x;
}
__device__ __forceinline__ float e4m3f(unsigned int b) {
    __hip_fp8_e4m3 h; h.__x = (__hip_fp8_storage_t)b;
    return (float)h;
}
__device__ __forceinline__ unsigned int pk4_e4m3(const float* v) {
    return (unsigned)f2e4m3(v[0]) | ((unsigned)f2e4m3(v[1]) << 8) |
           ((unsigned)f2e4m3(v[2]) << 16) | ((unsigned)f2e4m3(v[3]) << 24);
}

// ---------------- norm of wfft (closed form via Parseval) ----------------
__global__ void norm_part(const float* __restrict__ w, float* __restrict__ red) {
    int idx = blockIdx.x * 256 + threadIdx.x;
    const float* wp = w + (size_t)idx * 9;
    float s2 = 0.f, aa = 0.f, bb = 0.f;
#pragma unroll
    for (int u = 0; u < 3; u++) {
        float w0 = wp[u*3+0], w1 = wp[u*3+1], w2 = wp[u*3+2];
        s2 += w0*w0 + w1*w1 + w2*w2;
        float au = w0 + w1 + w2, bu = w0 - w1 + w2;
        aa += au*au; bb += bu*bu;
    }
    float p = 512.f*s2 + 16.f*(aa + bb);
    __shared__ float sm[256];
    sm[threadIdx.x] = p; __syncthreads();
    for (int s = 128; s > 0; s >>= 1) {
        if (threadIdx.x < s) sm[threadIdx.x] += sm[threadIdx.x + s];
        __syncthreads();
    }
    if (threadIdx.x == 0) red[blockIdx.x] = sm[0];
}

__global__ void norm_final(const float* __restrict__ red, const float* __restrict__ alpha,
                           float* __restrict__ sig) {
    __shared__ float sm[256];
    sm[threadIdx.x] = red[threadIdx.x]; __syncthreads();
    for (int s = 128; s > 0; s >>= 1) {
        if (threadIdx.x < s) sm[threadIdx.x] += sm[threadIdx.x + s];
        __syncthreads();
    }
    if (threadIdx.x == 0) sig[0] = alpha[0] / sqrtf(sm[0]);
}

// ---------------- H fragments (A-operand: m=o, k=c), bf16 ----------------
__global__ void hfrag_build(const float* __restrict__ H, unsigned short* __restrict__ Hfrag) {
    int kk = blockIdx.x, mt = blockIdx.y, lane = threadIdx.x;   // 64 threads
    int o = mt*16 + (lane & 15), c0 = kk*32 + (lane >> 4)*8;
    const float* hp = H + (size_t)o*NCH + c0;
    uint4 u;
    u.x = pack2(hp[0], hp[1]); u.y = pack2(hp[2], hp[3]);
    u.z = pack2(hp[4], hp[5]); u.w = pack2(hp[6], hp[7]);
    ((uint4*)Hfrag)[((size_t)kk*16 + mt)*64 + lane] = u;
}

// ---------------- rfft2: register-resident DFT, 8 tiles per 256-thread block ----------------
// step-1 uses real-input even/odd symmetry (halves its FMAs); step-2 radix-2.
// NOTE: no min-waves arg — (256,4) forced VGPR 64 and spilled (R9: 4x slower).
__global__ __launch_bounds__(256) void rfft2_reg(const float* __restrict__ x,
                                                 float2* __restrict__ tmp)
{
    __shared__ float2 T[8][544];       // [half][r*17+j], ~35 KB
    __shared__ float wc[32], wsn[32];
    int t = threadIdx.x;
    int half = t >> 5, lane = t & 31;
    int cb = blockIdx.x * 8 + half;    // tile index in tmp order: cb = c*32 + b
    int c = cb >> 5, b = cb & 31;
    if (t < 32) { wc[t] = COS32[t]; wsn[t] = SIN32[t]; }
    float xr[32];
    const float* xp = x + ((size_t)(b * NCH + c)) * 1024 + lane * 32;
#pragma unroll
    for (int q = 0; q < 8; q++) {
        float4 v = *(const float4*)(xp + q*4);
        xr[q*4+0] = v.x; xr[q*4+1] = v.y; xr[q*4+2] = v.z; xr[q*4+3] = v.w;
    }
    // even/odd split: es = x_s + x_{32-s}, os = x_s - x_{32-s}
    float x0v = xr[0], x16v = xr[16];
    float es[15], os[15];
#pragma unroll
    for (int s = 1; s <= 15; s++) { es[s-1] = xr[s] + xr[32-s]; os[s-1] = xr[s] - xr[32-s]; }
    // step 1: T[r=lane][j] (constant twiddles)
#pragma unroll
    for (int j = 0; j < 17; j++) {
        float ax = x0v + ((j & 1) ? -x16v : x16v);
        float ay = 0.f;
#pragma unroll
        for (int s = 1; s <= 15; s++) {
            int m = (j * s) & 31;
            ax += es[s-1] * COS32[m];
            ay -= os[s-1] * SIN32[m];
        }
        T[half][lane*17 + j] = make_float2(ax, ay);
    }
    __syncthreads();
    float wr_[16], wi_[16];
#pragma unroll
    for (int r = 0; r < 16; r++) {
        int m = (lane * r) & 31;
        wr_[r] = wc[m]; wi_[r] = wsn[m];
    }
    float sgn = (lane & 1) ? -1.f : 1.f;    // (-1)^i
    // step 2: z[i=lane][j] = sum_{r<16} e^{-2pi i i r/32} (T[r][j] + (-1)^i T[r+16][j])
    float2* op = tmp + (size_t)cb * 544 + lane * 17;
#pragma unroll
    for (int j = 0; j < 17; j++) {
        float ax = 0.f, ay = 0.f;
#pragma unroll
        for (int r = 0; r < 16; r++) {
            float2 t1 = T[half][r*17 + j];
            float2 t2 = T[half][(r+16)*17 + j];
            float ex = fmaf(sgn, t2.x, t1.x);
            float ey = fmaf(sgn, t2.y, t1.y);
            ax += ex * wr_[r] + ey * wi_[r];
            ay += ey * wr_[r] - ex * wi_[r];
        }
        op[j] = make_float2(ax, ay);
    }
}

// ---------------- transpose tmp[cb][f] -> fp32 planes + fp8 planes [f][b][c] ----------------
__global__ __launch_bounds__(256) void transpose_z(const float2* __restrict__ tmp,
        float* __restrict__ z32r, float* __restrict__ z32i,
        unsigned char* __restrict__ z8r, unsigned char* __restrict__ z8i)
{
    __shared__ float2 tile[32][33];
    int ct = blockIdx.x, ft = blockIdx.y, b = blockIdx.z;
    int t = threadIdx.x;
#pragma unroll
    for (int it = 0; it < 4; it++) {
        int idx = t + it*256; int cl = idx >> 5, fl = idx & 31;
        tile[cl][fl] = tmp[((size_t)((ct*32 + cl)*32 + b))*544 + ft*32 + fl];
    }
    __syncthreads();
#pragma unroll
    for (int it = 0; it < 4; it++) {
        int idx = t + it*256; int fl = idx >> 5, cl = idx & 31;
        float2 v = tile[cl][fl];
        size_t zi_ = ((size_t)(ft*32 + fl)*NB + b)*NCH + ct*32 + cl;
        z32r[zi_] = v.x; z32i[zi_] = v.y;
        z8r[zi_] = f2e4m3(v.x); z8i[zi_] = f2e4m3(v.y);
    }
}

// ---------------- A-build into fp8 MFMA fragment order (scaled by 2^16) ----------------
__global__ __launch_bounds__(256) void a_build_frag(const float* __restrict__ w,
        const float* __restrict__ sig, unsigned char* __restrict__ Afrag)
{
    __shared__ float2 wtab[32];
    __shared__ unsigned char lar[512], lai[512];
    int t = threadIdx.x;
    if (t < 32) {
        float ph = -2.f * PI_F * (float)t / 32.f;
        wtab[t] = make_float2(cosf(ph), sinf(ph));
    }
    int mt = blockIdx.x, kk = blockIdx.y, fs = blockIdx.z;
    int c = mt*16 + (t & 15), cpl = t >> 4;
    int cpA = kk*32 + cpl, cpB = cpA + 16;
    float ua[9], va[9], ub[9], vb[9];
    {
        const float* pa1 = w + ((size_t)c*NCH + cpA)*9;
        const float* pb1 = w + ((size_t)c*NCH + cpB)*9;
        const float* pa2 = w + ((size_t)cpA*NCH + c)*9;
        const float* pb2 = w + ((size_t)cpB*NCH + c)*9;
#pragma unroll
        for (int q = 0; q < 9; q++) {
            float w1a = pa1[q], w2a = pa2[q], w1b = pb1[q], w2b = pb2[q];
            ua[q] = w1a - w2a; va[q] = w1a + w2a;
            ub[q] = w1b - w2b; vb[q] = w1b + w2b;
        }
    }
    float sS = sig[0] * ASCALE;
    int la_ = ((c & 15) + 16*(cpl>>3))*8 + (cpl & 7);
    int lb_ = la_ + 32*8;
    __syncthreads();
    for (int fl = fs*68; fl < fs*68 + 68; fl++) {
        int i = fl / 17, jj = fl - i * 17;    // f = i*17 + j ordering
        int m_[9];
        m_[0] = (i + jj) & 31;  m_[1] = i;             m_[2] = (i - jj) & 31;
        m_[3] = jj;             m_[4] = 0;             m_[5] = (32 - jj) & 31;
        m_[6] = (jj - i) & 31;  m_[7] = (32 - i) & 31; m_[8] = (64 - i - jj) & 31;
        float ArA = 0.f, AiA = 0.f, ArB = 0.f, AiB = 0.f;
#pragma unroll
        for (int q = 0; q < 9; q++) {
            float2 P = wtab[m_[q]];
            ArA += ua[q] * P.x; AiA += va[q] * P.y;
            ArB += ub[q] * P.x; AiB += vb[q] * P.y;
        }
        lar[la_] = f2e4m3(sS*ArA); lai[la_] = f2e4m3(sS*AiA);
        lar[lb_] = f2e4m3(sS*ArB); lai[lb_] = f2e4m3(sS*AiB);
        __syncthreads();
        size_t bch = (((size_t)fl*8 + kk)*16 + mt)*256;   // uint units (1024 B/fragment)
        ((unsigned int*)Afrag)[bch + t] = (t < 128) ? ((const unsigned int*)lar)[t]
                                                    : ((const unsigned int*)lai)[t - 128];
        __syncthreads();
    }
}

// ---------------- neum1: t = z - A z  (fp8 A & z, t out fp8) ----------------
__global__ __launch_bounds__(256) void neum1(
    const unsigned char* __restrict__ Afrag,
    const unsigned char* __restrict__ z8r, const unsigned char* __restrict__ z8i,
    unsigned char* __restrict__ outR, unsigned char* __restrict__ outI)
{
    __shared__ uint2 lz8[2][1024];   // 16 KB, swizzled fp8
    int fl = blockIdx.x >> 1, half = blockIdx.x & 1;
    int f = fl;
    int t = threadIdx.x;
    const uint2* s0 = (const uint2*)(z8r + (size_t)f*8192);
    const uint2* s1 = (const uint2*)(z8i + (size_t)f*8192);
    for (int u = t; u < 2048; u += 256) {
        int p = u >> 10, idx = u & 1023;
        int b = idx >> 5, o16 = idx & 31;
        lz8[p][b*32 + (o16 ^ (b & 7))] = (p ? s1 : s0)[idx];
    }
    __syncthreads();
    int w = t >> 6, lane = t & 63, lo = lane & 15, hi = lane >> 4;
    f32x4 accr[2][2], acci[2][2];
    f32x4 zz = {0.f, 0.f, 0.f, 0.f};
#pragma unroll
    for (int mt = 0; mt < 2; mt++)
#pragma unroll
        for (int nt = 0; nt < 2; nt++) { accr[mt][nt] = zz; acci[mt][nt] = zz; }
    const uint2* A8 = (const uint2*)Afrag;
    for (int kk = 0; kk < 8; kk++) {
        long ar[2], ai[2], ain[2];
#pragma unroll
        for (int mt = 0; mt < 2; mt++) {
            int mtg = half*8 + w*2 + mt;
            size_t idx = (((size_t)fl*8 + kk)*16 + mtg)*128 + lane;
            uint2 va = A8[idx], vb = A8[idx + 64];
            ar[mt] = __builtin_bit_cast(long, va);
            ai[mt] = __builtin_bit_cast(long, vb);
            uint2 vn = make_uint2(vb.x ^ 0x80808080u, vb.y ^ 0x80808080u);
            ain[mt] = __builtin_bit_cast(long, vn);
        }
        long zr[2], zi_[2];
#pragma unroll
        for (int nt = 0; nt < 2; nt++) {
            int b = nt*16 + lo;
            int du = b*32 + ((kk*4 + hi) ^ (b & 7));
            zr[nt]  = __builtin_bit_cast(long, lz8[0][du]);
            zi_[nt] = __builtin_bit_cast(long, lz8[1][du]);
        }
#pragma unroll
        for (int mt = 0; mt < 2; mt++)
#pragma unroll
            for (int nt = 0; nt < 2; nt++) {
                accr[mt][nt] = __builtin_amdgcn_mfma_f32_16x16x32_fp8_fp8(ar[mt],  zr[nt],  accr[mt][nt], 0, 0, 0);
                accr[mt][nt] = __builtin_amdgcn_mfma_f32_16x16x32_fp8_fp8(ain[mt], zi_[nt], accr[mt][nt], 0, 0, 0);
                acci[mt][nt] = __builtin_amdgcn_mfma_f32_16x16x32_fp8_fp8(ar[mt],  zi_[nt], acci[mt][nt], 0, 0, 0);
                acci[mt][nt] = __builtin_amdgcn_mfma_f32_16x16x32_fp8_fp8(ai[mt],  zr[nt],  acci[mt][nt], 0, 0, 0);
            }
    }
#pragma unroll
    for (int mt = 0; mt < 2; mt++)
#pragma unroll
        for (int nt = 0; nt < 2; nt++) {
            int c0 = half*128 + w*32 + mt*16 + hi*4;
            int b  = nt*16 + lo;
            int duc = b*32 + (((c0 & 255) >> 3) ^ (b & 7));
            int sel = (c0 >> 2) & 1;
            uint2 q0 = lz8[0][duc], q1 = lz8[1][duc];
            unsigned qr = sel ? q0.y : q0.x;
            unsigned qi = sel ? q1.y : q1.x;
            float zfr[4] = { e4m3f(qr & 0xffu), e4m3f((qr>>8)&0xffu),
                             e4m3f((qr>>16)&0xffu), e4m3f(qr>>24) };
            float zfi[4] = { e4m3f(qi & 0xffu), e4m3f((qi>>8)&0xffu),
                             e4m3f((qi>>16)&0xffu), e4m3f(qi>>24) };
            size_t zb = ((size_t)f*NB + b)*NCH + c0;
            float vr[4], vi[4];
#pragma unroll
            for (int jj = 0; jj < 4; jj++) {
                vr[jj] = zfr[jj] - accr[mt][nt][jj] * INV_ASCALE;
                vi[jj] = zfi[jj] - acci[mt][nt][jj] * INV_ASCALE;
            }
            *(unsigned int*)(outR + zb) = pk4_e4m3(vr);
            *(unsigned int*)(outI + zb) = pk4_e4m3(vi);
        }
}

// ---------------- neum2h: wx = z32 - 2 A t  ->  wxh = H wx  (fused, full f per block) ----------------
__global__ __launch_bounds__(512) void neum2h(
    const unsigned char* __restrict__ Afrag,
    const unsigned short* __restrict__ Hfrag,
    const unsigned char* __restrict__ TR, const unsigned char* __restrict__ TI,
    const float* __restrict__ z32r, const float* __restrict__ z32i,
    unsigned short* __restrict__ wxhR, unsigned short* __restrict__ wxhI)
{
    __shared__ uint2 lz8[2][1024];   // 16 KB fp8 t
    __shared__ uint4 lw[2][1024];    // 32 KB bf16 wx
    int fl = blockIdx.x;
    int f = fl;
    int t = threadIdx.x;
    const uint2* s0 = (const uint2*)(TR + (size_t)f*8192);
    const uint2* s1 = (const uint2*)(TI + (size_t)f*8192);
    for (int u = t; u < 2048; u += 512) {
        int p = u >> 10, idx = u & 1023;
        int b = idx >> 5, o16 = idx & 31;
        lz8[p][b*32 + (o16 ^ (b & 7))] = (p ? s1 : s0)[idx];
    }
    __syncthreads();
    int w = t >> 6, lane = t & 63, lo = lane & 15, hi = lane >> 4;
    const uint2* A8 = (const uint2*)Afrag;
    const uint4* H4 = (const uint4*)Hfrag;
    f32x4 accr[2][2], acci[2][2];
    f32x4 zz = {0.f, 0.f, 0.f, 0.f};
#pragma unroll
    for (int mt = 0; mt < 2; mt++)
#pragma unroll
        for (int nt = 0; nt < 2; nt++) { accr[mt][nt] = zz; acci[mt][nt] = zz; }
    // ---- matmul 1: acc = A * t (fp8) ----
    for (int kk = 0; kk < 8; kk++) {
        long ar[2], ai[2], ain[2];
#pragma unroll
        for (int mt = 0; mt < 2; mt++) {
            int mtg = w*2 + mt;
            size_t idx = (((size_t)fl*8 + kk)*16 + mtg)*128 + lane;
            uint2 va = A8[idx], vb = A8[idx + 64];
            ar[mt] = __builtin_bit_cast(long, va);
            ai[mt] = __builtin_bit_cast(long, vb);
            uint2 vn = make_uint2(vb.x ^ 0x80808080u, vb.y ^ 0x80808080u);
            ain[mt] = __builtin_bit_cast(long, vn);
        }
        long zr[2], zi_[2];
#pragma unroll
        for (int nt = 0; nt < 2; nt++) {
            int b = nt*16 + lo;
            int du = b*32 + ((kk*4 + hi) ^ (b & 7));
            zr[nt]  = __builtin_bit_cast(long, lz8[0][du]);
            zi_[nt] = __builtin_bit_cast(long, lz8[1][du]);
        }
#pragma unroll
        for (int mt = 0; mt < 2; mt++)
#pragma unroll
            for (int nt = 0; nt < 2; nt++) {
                accr[mt][nt] = __builtin_amdgcn_mfma_f32_16x16x32_fp8_fp8(ar[mt],  zr[nt],  accr[mt][nt], 0, 0, 0);
                accr[mt][nt] = __builtin_amdgcn_mfma_f32_16x16x32_fp8_fp8(ain[mt], zi_[nt], accr[mt][nt], 0, 0, 0);
                acci[mt][nt] = __builtin_amdgcn_mfma_f32_16x16x32_fp8_fp8(ar[mt],  zi_[nt], acci[mt][nt], 0, 0, 0);
                acci[mt][nt] = __builtin_amdgcn_mfma_f32_16x16x32_fp8_fp8(ai[mt],  zr[nt],  acci[mt][nt], 0, 0, 0);
            }
    }
    __syncthreads();
    // ---- epilogue 1: wx = z32 - 2 acc/S; write bf16 wx into LDS ----
#pragma unroll
    for (int mt = 0; mt < 2; mt++)
#pragma unroll
        for (int nt = 0; nt < 2; nt++) {
            int c0 = w*32 + mt*16 + hi*4;
            int b  = nt*16 + lo;
            size_t zb = ((size_t)f*NB + b)*NCH + c0;
            float4 z4r = *(const float4*)(z32r + zb);
            float4 z4i = *(const float4*)(z32i + zb);
            const float k2 = 2.f * INV_ASCALE;
            float vr[4] = { z4r.x - k2*accr[mt][nt][0], z4r.y - k2*accr[mt][nt][1],
                            z4r.z - k2*accr[mt][nt][2], z4r.w - k2*accr[mt][nt][3] };
            float vi[4] = { z4i.x - k2*acci[mt][nt][0], z4i.y - k2*acci[mt][nt][1],
                            z4i.z - k2*acci[mt][nt][2], z4i.w - k2*acci[mt][nt][3] };
            int o16c = c0 >> 3;
            int duc = b*32 + (o16c ^ (b & 7));
            int sel = (c0 >> 2) & 1;
            ((uint2*)&lw[0][duc])[sel] = make_uint2(pack2(vr[0], vr[1]), pack2(vr[2], vr[3]));
            ((uint2*)&lw[1][duc])[sel] = make_uint2(pack2(vi[0], vi[1]), pack2(vi[2], vi[3]));
        }
    __syncthreads();
    // ---- matmul 2: wxh = H * wx (bf16) ----
#pragma unroll
    for (int mt = 0; mt < 2; mt++)
#pragma unroll
        for (int nt = 0; nt < 2; nt++) { accr[mt][nt] = zz; acci[mt][nt] = zz; }
    for (int kk = 0; kk < 8; kk++) {
        bf16x8 hm[2];
#pragma unroll
        for (int mt = 0; mt < 2; mt++) {
            int mtg = w*2 + mt;
            hm[mt] = __builtin_bit_cast(bf16x8, H4[((size_t)kk*16 + mtg)*64 + lane]);
        }
        bf16x8 zr[2], zi_[2];
#pragma unroll
        for (int nt = 0; nt < 2; nt++) {
            int b = nt*16 + lo;
            int du = b*32 + ((kk*4 + hi) ^ (b & 7));
            zr[nt]  = __builtin_bit_cast(bf16x8, lw[0][du]);
            zi_[nt] = __builtin_bit_cast(bf16x8, lw[1][du]);
        }
#pragma unroll
        for (int mt = 0; mt < 2; mt++)
#pragma unroll
            for (int nt = 0; nt < 2; nt++) {
                accr[mt][nt] = __builtin_amdgcn_mfma_f32_16x16x32_bf16(hm[mt], zr[nt],  accr[mt][nt], 0, 0, 0);
                acci[mt][nt] = __builtin_amdgcn_mfma_f32_16x16x32_bf16(hm[mt], zi_[nt], acci[mt][nt], 0, 0, 0);
            }
    }
    // ---- epilogue 2: wxh bf16 planes, [f][b][o] layout ----
#pragma unroll
    for (int mt = 0; mt < 2; mt++)
#pragma unroll
        for (int nt = 0; nt < 2; nt++) {
            int o0 = w*32 + mt*16 + hi*4;
            int b  = nt*16 + lo;
            size_t zb = ((size_t)f*NB + b)*NCH + o0;
            *(uint2*)(wxhR + zb) = make_uint2(pack2(accr[mt][nt][0], accr[mt][nt][1]),
                                              pack2(accr[mt][nt][2], accr[mt][nt][3]));
            *(uint2*)(wxhI + zb) = make_uint2(pack2(acci[mt][nt][0], acci[mt][nt][1]),
                                              pack2(acci[mt][nt][2], acci[mt][nt][3]));
        }
}

// ---------------- pass I: complex ifft along i -> G[j][r][ob] (coalesced stores) ----------------
template<int RH>
__device__ __forceinline__ void ifft_i_body(const unsigned short* __restrict__ YR,
                                            const unsigned short* __restrict__ YI,
                                            float2* __restrict__ G, int j, int ob)
{
    float2 Gacc[16];
#pragma unroll
    for (int rr = 0; rr < 16; rr++) Gacc[rr] = make_float2(0.f, 0.f);
#pragma unroll
    for (int i = 0; i < 32; i++) {
        size_t yi_ = (size_t)(i * 17 + j) * 8192 + ob;
        float Yx = bf2f(YR[yi_]);
        float Yy = bf2f(YI[yi_]);
#pragma unroll
        for (int rr = 0; rr < 16; rr++) {
            int m = (i * (RH * 16 + rr)) & 31;     // compile-time constant
            Gacc[rr].x += Yx*COS32[m] - Yy*SIN32[m];
            Gacc[rr].y += Yx*SIN32[m] + Yy*COS32[m];
        }
    }
#pragma unroll
    for (int rr = 0; rr < 16; rr++) {
        G[((size_t)(j*32 + RH*16 + rr))*8192 + ob] =
            make_float2(Gacc[rr].x * (1.f/32.f), Gacc[rr].y * (1.f/32.f));
    }
}

__global__ __launch_bounds__(256) void ifft_i(const unsigned short* __restrict__ YR,
                                              const unsigned short* __restrict__ YI,
                                              float2* __restrict__ G) {
    int bid = blockIdx.x;
    int j   = bid >> 6;          // 0..16
    int rh  = (bid >> 5) & 1;    // 0..1
    int obc = bid & 31;          // 0..31
    int ob  = obc * 256 + threadIdx.x;
    if (rh == 0) ifft_i_body<0>(YR, YI, G, j, ob);
    else         ifft_i_body<1>(YR, YI, G, j, ob);
}

// ---------------- pass II: irfft along j + bias -> out[b][o][r][s] ----------------
// ob = b*256 + o (plane layout [f][b][o])
__global__ __launch_bounds__(256) void irfft_j(const float2* __restrict__ G,
                                               const float* __restrict__ bias,
                                               float* __restrict__ out) {
    int gid = blockIdx.x * 256 + threadIdx.x;
    int r = gid >> 13, ob = gid & 8191;
    int b = ob >> 8, o = ob & 255;
    float2 Gv[17];
#pragma unroll
    for (int jj = 0; jj < 17; jj++)
        Gv[jj] = G[((size_t)(jj*32 + r))*8192 + ob];
    float y[32];
    float g0 = Gv[0].x, g16 = Gv[16].x;
#pragma unroll
    for (int s = 0; s < 32; s++) y[s] = g0 + ((s & 1) ? -g16 : g16);
#pragma unroll
    for (int jj = 1; jj < 16; jj++) {
#pragma unroll
        for (int s = 0; s < 32; s++) {
            int m = (jj * s) & 31;                 // compile-time constant
            y[s] += 2.f * (Gv[jj].x * COS32[m] - Gv[jj].y * SIN32[m]);
        }
    }
    float bv = bias[o];
    float* op = out + ((size_t)(b * NCH + o) * 32 + r) * 32;
#pragma unroll
    for (int s = 0; s < 32; s++) op[s] = y[s] * (1.f/32.f) + bv;
}

extern "C" void kernel_launch(void* const* d_in, const int* in_sizes, int n_in,
                              void* d_out, int out_size, void* d_ws, size_t ws_size,
                              hipStream_t stream) {
    (void)in_sizes; (void)n_in; (void)out_size;
    if (ws_size < WS_NEED) return;

    const float* x     = (const float*)d_in[0];
    const float* w     = (const float*)d_in[1];
    const float* alpha = (const float*)d_in[2];
    const float* H     = (const float*)d_in[3];
    const float* bias  = (const float*)d_in[4];
    float* out = (float*)d_out;

    char* ws = (char*)d_ws;
    unsigned char* Afrag = (unsigned char*)(ws + OFF_AFRAG);
    float2* tmp = (float2*)(ws + OFF_AFRAG);   // dead before a_build writes Afrag
    float2* G   = (float2*)(ws + OFF_AFRAG);   // live after neum passes (Afrag dead)
    unsigned char* t8r  = (unsigned char*)(ws + OFF_T8R);
    unsigned char* t8i  = (unsigned char*)(ws + OFF_T8I);
    unsigned char* z8r  = (unsigned char*)(ws + OFF_Z8R);
    unsigned char* z8i  = (unsigned char*)(ws + OFF_Z8I);
    float* z32r = (float*)(ws + OFF_Z32R);
    float* z32i = (float*)(ws + OFF_Z32I);
    unsigned short* wxhR = (unsigned short*)(ws + OFF_WXHR);
    unsigned short* wxhI = (unsigned short*)(ws + OFF_WXHI);
    unsigned short* Hfrag = (unsigned short*)(ws + OFF_HFRAG);
    float* red = (float*)(ws + OFF_RED);
    float* sig = red + 256;

    norm_part<<<256, 256, 0, stream>>>(w, red);
    norm_final<<<1, 256, 0, stream>>>(red, alpha, sig);
    hfrag_build<<<dim3(8, 16), 64, 0, stream>>>(H, Hfrag);

    rfft2_reg<<<1024, 256, 0, stream>>>(x, tmp);
    transpose_z<<<dim3(8, 17, 32), 256, 0, stream>>>(tmp, z32r, z32i, z8r, z8i);

    a_build_frag<<<dim3(16, 8, 8), 256, 0, stream>>>(w, sig, Afrag);
    neum1<<<NF*2, 256, 0, stream>>>(Afrag, z8r, z8i, t8r, t8i);
    neum2h<<<NF, 512, 0, stream>>>(Afrag, Hfrag, t8r, t8i, z32r, z32i, wxhR, wxhI);

    ifft_i<<<1088, 256, 0, stream>>>(wxhR, wxhI, G);
    irfft_j<<<1024, 256, 0, stream>>>(G, bias, out);
}

// Round 12
// 181.978 us; speedup vs baseline: 2.2954x; 1.1992x over previous
//
#include <hip/hip_runtime.h>
#include <hip/hip_fp8.h>
#include <cstddef>

#define PI_F 3.14159265358979323846f

#define NCH 256   // C
#define NB  32    // B
#define NF  544   // n*(n/2+1),  f = i*17 + j

#define ASCALE     65536.0f
#define INV_ASCALE (1.0f/65536.0f)

typedef short  bf16x8 __attribute__((ext_vector_type(8)));
typedef float  f32x4  __attribute__((ext_vector_type(4)));

// ---- workspace layout (bytes), single-chunk, fp8 A ----
#define SZ_AFRAG ((size_t)NF*8*16*1024)         // 71,303,168 (fp8 fragments; tmp & G alias)
#define SZ_P8    ((size_t)NF*NB*NCH)            // 4,456,448  (fp8 plane)
#define SZ_PB    ((size_t)NF*NB*NCH*2)          // 8,912,896  (bf16 plane)
#define SZ_P32   ((size_t)NF*NB*NCH*4)          // 17,825,792 (fp32 plane)
#define OFF_AFRAG ((size_t)0)
#define OFF_T8R  (OFF_AFRAG + SZ_AFRAG)
#define OFF_T8I  (OFF_T8R + SZ_P8)
#define OFF_Z8R  (OFF_T8I + SZ_P8)
#define OFF_Z8I  (OFF_Z8R + SZ_P8)
#define OFF_Z32R (OFF_Z8I + SZ_P8)
#define OFF_Z32I (OFF_Z32R + SZ_P32)
#define OFF_WXHR (OFF_Z32I + SZ_P32)
#define OFF_WXHI (OFF_WXHR + SZ_PB)
#define OFF_HFRAG (OFF_WXHI + SZ_PB)
#define SZ_HFRAG ((size_t)8*16*1024)            // 131,072
#define OFF_RED  (OFF_HFRAG + SZ_HFRAG)
#define WS_NEED  (OFF_RED + (size_t)4096)       // ~142.7 MB

// 32-point twiddle tables: COS32[k]=cos(2pi k/32), SIN32[k]=sin(2pi k/32)
__device__ constexpr float COS32[32] = {
     1.0000000000f,  0.9807852804f,  0.9238795325f,  0.8314696123f,
     0.7071067812f,  0.5555702330f,  0.3826834324f,  0.1950903220f,
     0.0000000000f, -0.1950903220f, -0.3826834324f, -0.5555702330f,
    -0.7071067812f, -0.8314696123f, -0.9238795325f, -0.9807852804f,
    -1.0000000000f, -0.9807852804f, -0.9238795325f, -0.8314696123f,
    -0.7071067812f, -0.5555702330f, -0.3826834324f, -0.1950903220f,
    -0.0000000000f,  0.1950903220f,  0.3826834324f,  0.5555702330f,
     0.7071067812f,  0.8314696123f,  0.9238795325f,  0.9807852804f };
__device__ constexpr float SIN32[32] = {
     0.0000000000f,  0.1950903220f,  0.3826834324f,  0.5555702330f,
     0.7071067812f,  0.8314696123f,  0.9238795325f,  0.9807852804f,
     1.0000000000f,  0.9807852804f,  0.9238795325f,  0.8314696123f,
     0.7071067812f,  0.5555702330f,  0.3826834324f,  0.1950903220f,
     0.0000000000f, -0.1950903220f, -0.3826834324f, -0.5555702330f,
    -0.7071067812f, -0.8314696123f, -0.9238795325f, -0.9807852804f,
    -1.0000000000f, -0.9807852804f, -0.9238795325f, -0.8314696123f,
    -0.7071067812f, -0.5555702330f, -0.3826834324f, -0.1950903220f };

__device__ __forceinline__ unsigned short f2bf(float x) {
    unsigned int u = __float_as_uint(x);
    u += 0x7FFFu + ((u >> 16) & 1u);            // RNE
    return (unsigned short)(u >> 16);
}
__device__ __forceinline__ float bf2f(unsigned int h) {
    return __uint_as_float(h << 16);
}
__device__ __forceinline__ unsigned int pack2(float a, float b) {
    return (unsigned int)f2bf(a) | ((unsigned int)f2bf(b) << 16);
}
__device__ __forceinline__ unsigned char f2e4m3(float x) {
    __hip_fp8_e4m3 h(x);
    return (unsigned char)h.__x;
}
__device__ __forceinline__ float e4m3f(unsigned int b) {
    __hip_fp8_e4m3 h; h.__x = (__hip_fp8_storage_t)b;
    return (float)h;
}
__device__ __forceinline__ unsigned int pk4_e4m3(const float* v) {
    return (unsigned)f2e4m3(v[0]) | ((unsigned)f2e4m3(v[1]) << 8) |
           ((unsigned)f2e4m3(v[2]) << 16) | ((unsigned)f2e4m3(v[3]) << 24);
}

// ---------------- norm of wfft (closed form via Parseval) ----------------
__global__ void norm_part(const float* __restrict__ w, float* __restrict__ red) {
    int idx = blockIdx.x * 256 + threadIdx.x;
    const float* wp = w + (size_t)idx * 9;
    float s2 = 0.f, aa = 0.f, bb = 0.f;
#pragma unroll
    for (int u = 0; u < 3; u++) {
        float w0 = wp[u*3+0], w1 = wp[u*3+1], w2 = wp[u*3+2];
        s2 += w0*w0 + w1*w1 + w2*w2;
        float au = w0 + w1 + w2, bu = w0 - w1 + w2;
        aa += au*au; bb += bu*bu;
    }
    float p = 512.f*s2 + 16.f*(aa + bb);
    __shared__ float sm[256];
    sm[threadIdx.x] = p; __syncthreads();
    for (int s = 128; s > 0; s >>= 1) {
        if (threadIdx.x < s) sm[threadIdx.x] += sm[threadIdx.x + s];
        __syncthreads();
    }
    if (threadIdx.x == 0) red[blockIdx.x] = sm[0];
}

__global__ void norm_final(const float* __restrict__ red, const float* __restrict__ alpha,
                           float* __restrict__ sig) {
    __shared__ float sm[256];
    sm[threadIdx.x] = red[threadIdx.x]; __syncthreads();
    for (int s = 128; s > 0; s >>= 1) {
        if (threadIdx.x < s) sm[threadIdx.x] += sm[threadIdx.x + s];
        __syncthreads();
    }
    if (threadIdx.x == 0) sig[0] = alpha[0] / sqrtf(sm[0]);
}

// ---------------- H fragments (A-operand: m=o, k=c), bf16 ----------------
__global__ void hfrag_build(const float* __restrict__ H, unsigned short* __restrict__ Hfrag) {
    int kk = blockIdx.x, mt = blockIdx.y, lane = threadIdx.x;   // 64 threads
    int o = mt*16 + (lane & 15), c0 = kk*32 + (lane >> 4)*8;
    const float* hp = H + (size_t)o*NCH + c0;
    uint4 u;
    u.x = pack2(hp[0], hp[1]); u.y = pack2(hp[2], hp[3]);
    u.z = pack2(hp[4], hp[5]); u.w = pack2(hp[6], hp[7]);
    ((uint4*)Hfrag)[((size_t)kk*16 + mt)*64 + lane] = u;
}

// ---------------- rfft2: register-resident DFT, 8 tiles per 256-thread block ----------------
// NOTE: no min-waves arg — (256,4) forced VGPR 64 and spilled (R9: 4x slower).
__global__ __launch_bounds__(256) void rfft2_reg(const float* __restrict__ x,
                                                 float2* __restrict__ tmp)
{
    __shared__ float2 T[8][544];       // [half][r*17+j], ~35 KB
    __shared__ float wc[32], wsn[32];
    int t = threadIdx.x;
    int half = t >> 5, lane = t & 31;
    int cb = blockIdx.x * 8 + half;    // tile index in tmp order: cb = c*32 + b
    int c = cb >> 5, b = cb & 31;
    if (t < 32) { wc[t] = COS32[t]; wsn[t] = SIN32[t]; }
    float xr[32];
    const float* xp = x + ((size_t)(b * NCH + c)) * 1024 + lane * 32;
#pragma unroll
    for (int q = 0; q < 8; q++) {
        float4 v = *(const float4*)(xp + q*4);
        xr[q*4+0] = v.x; xr[q*4+1] = v.y; xr[q*4+2] = v.z; xr[q*4+3] = v.w;
    }
    float x0v = xr[0], x16v = xr[16];
    float es[15], os[15];
#pragma unroll
    for (int s = 1; s <= 15; s++) { es[s-1] = xr[s] + xr[32-s]; os[s-1] = xr[s] - xr[32-s]; }
#pragma unroll
    for (int j = 0; j < 17; j++) {
        float ax = x0v + ((j & 1) ? -x16v : x16v);
        float ay = 0.f;
#pragma unroll
        for (int s = 1; s <= 15; s++) {
            int m = (j * s) & 31;
            ax += es[s-1] * COS32[m];
            ay -= os[s-1] * SIN32[m];
        }
        T[half][lane*17 + j] = make_float2(ax, ay);
    }
    __syncthreads();
    float wr_[16], wi_[16];
#pragma unroll
    for (int r = 0; r < 16; r++) {
        int m = (lane * r) & 31;
        wr_[r] = wc[m]; wi_[r] = wsn[m];
    }
    float sgn = (lane & 1) ? -1.f : 1.f;    // (-1)^i
    float2* op = tmp + (size_t)cb * 544 + lane * 17;
#pragma unroll
    for (int j = 0; j < 17; j++) {
        float ax = 0.f, ay = 0.f;
#pragma unroll
        for (int r = 0; r < 16; r++) {
            float2 t1 = T[half][r*17 + j];
            float2 t2 = T[half][(r+16)*17 + j];
            float ex = fmaf(sgn, t2.x, t1.x);
            float ey = fmaf(sgn, t2.y, t1.y);
            ax += ex * wr_[r] + ey * wi_[r];
            ay += ey * wr_[r] - ex * wi_[r];
        }
        op[j] = make_float2(ax, ay);
    }
}

// ---------------- transpose tmp[cb][f] -> fp32 planes + fp8 planes [f][b][c] ----------------
__global__ __launch_bounds__(256) void transpose_z(const float2* __restrict__ tmp,
        float* __restrict__ z32r, float* __restrict__ z32i,
        unsigned char* __restrict__ z8r, unsigned char* __restrict__ z8i)
{
    __shared__ float2 tile[32][33];
    int ct = blockIdx.x, ft = blockIdx.y, b = blockIdx.z;
    int t = threadIdx.x;
#pragma unroll
    for (int it = 0; it < 4; it++) {
        int idx = t + it*256; int cl = idx >> 5, fl = idx & 31;
        tile[cl][fl] = tmp[((size_t)((ct*32 + cl)*32 + b))*544 + ft*32 + fl];
    }
    __syncthreads();
#pragma unroll
    for (int it = 0; it < 4; it++) {
        int idx = t + it*256; int fl = idx >> 5, cl = idx & 31;
        float2 v = tile[cl][fl];
        size_t zi_ = ((size_t)(ft*32 + fl)*NB + b)*NCH + ct*32 + cl;
        z32r[zi_] = v.x; z32i[zi_] = v.y;
        z8r[zi_] = f2e4m3(v.x); z8i[zi_] = f2e4m3(v.y);
    }
}

// ---------------- A-build, factorized + direct fragment writes (no LDS, no barriers) ----------------
// A(f)_cc' = sS*[Sum_uv ua_uv cos th - i Sum_uv va_uv sin th], th = (1-u)phi + (1-v)psi,
// phi = 2pi*i/32, psi = 2pi*j/32. Factorized: 2 FMA per output byte.
// Fragment byte b of plane: m=(b>>3)&15 (c), k=(b>>7)*8+(b&7) (cp). Thread t<128: real-plane
// word t; t>=128: imag word t-128. Word w: c = mt*16+((w>>1)&15), cp0 = kk*32+(w>>5)*8+(w&1)*4.
__global__ __launch_bounds__(256) void a_build_direct(const float* __restrict__ w,
        const float* __restrict__ sig, unsigned int* __restrict__ Afrag)
{
    int mt = blockIdx.x, kk = blockIdx.y, j = blockIdx.z;   // 16, 8, 17
    int t = threadIdx.x;
    int wv = t & 127;
    int c   = mt*16 + ((wv >> 1) & 15);
    int cp0 = kk*32 + (wv >> 5)*8 + (wv & 1)*4;
    bool isReal = (t < 128);
    float sS = sig[0] * ASCALE;
    float sgnS = isReal ? sS : -sS;
    f32x4 P1, P2, P3, P4, P5;
#pragma unroll
    for (int e = 0; e < 4; e++) {
        int cp = cp0 + e;
        const float* p1 = w + ((size_t)c*NCH + cp)*9;
        const float* p2 = w + ((size_t)cp*NCH + c)*9;
        float u_[9];
#pragma unroll
        for (int q = 0; q < 9; q++)
            u_[q] = isReal ? (p1[q] - p2[q]) : (p1[q] + p2[q]);
        if (isReal) {
            // Ar = q1 + cpsi*q2 + cphi*(q3 + cpsi*q4) + sphi*(spsi*q5)
            P1[e] = sgnS * u_[4];
            P2[e] = sgnS * (u_[3] + u_[5]);
            P3[e] = sgnS * (u_[1] + u_[7]);
            P4[e] = sgnS * (u_[0] + u_[2] + u_[6] + u_[8]);
            P5[e] = sgnS * ((u_[6] - u_[8]) - (u_[0] - u_[2]));
        } else {
            // Ai = -[spsi*r1 + cphi*spsi*r2 + sphi*(r3 + cpsi*r4)]  (minus folded into sgnS)
            P1[e] = sgnS * (u_[3] - u_[5]);
            P2[e] = sgnS * ((u_[0] - u_[2]) + (u_[6] - u_[8]));
            P3[e] = sgnS * (u_[1] - u_[7]);
            P4[e] = sgnS * ((u_[0] + u_[2]) - (u_[6] + u_[8]));
            P5[e] = 0.f;
        }
    }
    float cps = COS32[j], sns = SIN32[j];
    f32x4 Aj, Bj, Cj;
    if (isReal) { Aj = P1 + cps*P2; Bj = P3 + cps*P4; Cj = sns*P5; }
    else        { Aj = sns*P1;      Bj = sns*P2;      Cj = P3 + cps*P4; }
    unsigned int* out = Afrag + ((size_t)j*128 + kk*16 + mt)*256 + t;
#pragma unroll
    for (int i = 0; i < 32; i++) {
        f32x4 v = Aj + COS32[i]*Bj + SIN32[i]*Cj;   // compile-time twiddles
        *out = (unsigned)f2e4m3(v[0]) | ((unsigned)f2e4m3(v[1]) << 8)
             | ((unsigned)f2e4m3(v[2]) << 16) | ((unsigned)f2e4m3(v[3]) << 24);
        out += (size_t)17*32768;   // fl = i*17 + j: +17 fragments per i-step
    }
}

// ---------------- neum1: t = z - A z  (fp8 A & z, t out fp8) ----------------
__global__ __launch_bounds__(256) void neum1(
    const unsigned char* __restrict__ Afrag,
    const unsigned char* __restrict__ z8r, const unsigned char* __restrict__ z8i,
    unsigned char* __restrict__ outR, unsigned char* __restrict__ outI)
{
    __shared__ uint2 lz8[2][1024];   // 16 KB, swizzled fp8
    int fl = blockIdx.x >> 1, half = blockIdx.x & 1;
    int f = fl;
    int t = threadIdx.x;
    const uint2* s0 = (const uint2*)(z8r + (size_t)f*8192);
    const uint2* s1 = (const uint2*)(z8i + (size_t)f*8192);
    for (int u = t; u < 2048; u += 256) {
        int p = u >> 10, idx = u & 1023;
        int b = idx >> 5, o16 = idx & 31;
        lz8[p][b*32 + (o16 ^ (b & 7))] = (p ? s1 : s0)[idx];
    }
    __syncthreads();
    int w = t >> 6, lane = t & 63, lo = lane & 15, hi = lane >> 4;
    f32x4 accr[2][2], acci[2][2];
    f32x4 zz = {0.f, 0.f, 0.f, 0.f};
#pragma unroll
    for (int mt = 0; mt < 2; mt++)
#pragma unroll
        for (int nt = 0; nt < 2; nt++) { accr[mt][nt] = zz; acci[mt][nt] = zz; }
    const uint2* A8 = (const uint2*)Afrag;
    for (int kk = 0; kk < 8; kk++) {
        long ar[2], ai[2], ain[2];
#pragma unroll
        for (int mt = 0; mt < 2; mt++) {
            int mtg = half*8 + w*2 + mt;
            size_t idx = (((size_t)fl*8 + kk)*16 + mtg)*128 + lane;
            uint2 va = A8[idx], vb = A8[idx + 64];
            ar[mt] = __builtin_bit_cast(long, va);
            ai[mt] = __builtin_bit_cast(long, vb);
            uint2 vn = make_uint2(vb.x ^ 0x80808080u, vb.y ^ 0x80808080u);
            ain[mt] = __builtin_bit_cast(long, vn);
        }
        long zr[2], zi_[2];
#pragma unroll
        for (int nt = 0; nt < 2; nt++) {
            int b = nt*16 + lo;
            int du = b*32 + ((kk*4 + hi) ^ (b & 7));
            zr[nt]  = __builtin_bit_cast(long, lz8[0][du]);
            zi_[nt] = __builtin_bit_cast(long, lz8[1][du]);
        }
#pragma unroll
        for (int mt = 0; mt < 2; mt++)
#pragma unroll
            for (int nt = 0; nt < 2; nt++) {
                accr[mt][nt] = __builtin_amdgcn_mfma_f32_16x16x32_fp8_fp8(ar[mt],  zr[nt],  accr[mt][nt], 0, 0, 0);
                accr[mt][nt] = __builtin_amdgcn_mfma_f32_16x16x32_fp8_fp8(ain[mt], zi_[nt], accr[mt][nt], 0, 0, 0);
                acci[mt][nt] = __builtin_amdgcn_mfma_f32_16x16x32_fp8_fp8(ar[mt],  zi_[nt], acci[mt][nt], 0, 0, 0);
                acci[mt][nt] = __builtin_amdgcn_mfma_f32_16x16x32_fp8_fp8(ai[mt],  zr[nt],  acci[mt][nt], 0, 0, 0);
            }
    }
#pragma unroll
    for (int mt = 0; mt < 2; mt++)
#pragma unroll
        for (int nt = 0; nt < 2; nt++) {
            int c0 = half*128 + w*32 + mt*16 + hi*4;
            int b  = nt*16 + lo;
            int duc = b*32 + (((c0 & 255) >> 3) ^ (b & 7));
            int sel = (c0 >> 2) & 1;
            uint2 q0 = lz8[0][duc], q1 = lz8[1][duc];
            unsigned qr = sel ? q0.y : q0.x;
            unsigned qi = sel ? q1.y : q1.x;
            float zfr[4] = { e4m3f(qr & 0xffu), e4m3f((qr>>8)&0xffu),
                             e4m3f((qr>>16)&0xffu), e4m3f(qr>>24) };
            float zfi[4] = { e4m3f(qi & 0xffu), e4m3f((qi>>8)&0xffu),
                             e4m3f((qi>>16)&0xffu), e4m3f(qi>>24) };
            size_t zb = ((size_t)f*NB + b)*NCH + c0;
            float vr[4], vi[4];
#pragma unroll
            for (int jj = 0; jj < 4; jj++) {
                vr[jj] = zfr[jj] - accr[mt][nt][jj] * INV_ASCALE;
                vi[jj] = zfi[jj] - acci[mt][nt][jj] * INV_ASCALE;
            }
            *(unsigned int*)(outR + zb) = pk4_e4m3(vr);
            *(unsigned int*)(outI + zb) = pk4_e4m3(vi);
        }
}

// ---------------- neum2h: wx = z32 - 2 A t  ->  wxh = H wx  (fused, full f per block) ----------------
__global__ __launch_bounds__(512) void neum2h(
    const unsigned char* __restrict__ Afrag,
    const unsigned short* __restrict__ Hfrag,
    const unsigned char* __restrict__ TR, const unsigned char* __restrict__ TI,
    const float* __restrict__ z32r, const float* __restrict__ z32i,
    unsigned short* __restrict__ wxhR, unsigned short* __restrict__ wxhI)
{
    __shared__ uint2 lz8[2][1024];   // 16 KB fp8 t
    __shared__ uint4 lw[2][1024];    // 32 KB bf16 wx
    int fl = blockIdx.x;
    int f = fl;
    int t = threadIdx.x;
    const uint2* s0 = (const uint2*)(TR + (size_t)f*8192);
    const uint2* s1 = (const uint2*)(TI + (size_t)f*8192);
    for (int u = t; u < 2048; u += 512) {
        int p = u >> 10, idx = u & 1023;
        int b = idx >> 5, o16 = idx & 31;
        lz8[p][b*32 + (o16 ^ (b & 7))] = (p ? s1 : s0)[idx];
    }
    __syncthreads();
    int w = t >> 6, lane = t & 63, lo = lane & 15, hi = lane >> 4;
    const uint2* A8 = (const uint2*)Afrag;
    const uint4* H4 = (const uint4*)Hfrag;
    f32x4 accr[2][2], acci[2][2];
    f32x4 zz = {0.f, 0.f, 0.f, 0.f};
#pragma unroll
    for (int mt = 0; mt < 2; mt++)
#pragma unroll
        for (int nt = 0; nt < 2; nt++) { accr[mt][nt] = zz; acci[mt][nt] = zz; }
    // ---- matmul 1: acc = A * t (fp8) ----
    for (int kk = 0; kk < 8; kk++) {
        long ar[2], ai[2], ain[2];
#pragma unroll
        for (int mt = 0; mt < 2; mt++) {
            int mtg = w*2 + mt;
            size_t idx = (((size_t)fl*8 + kk)*16 + mtg)*128 + lane;
            uint2 va = A8[idx], vb = A8[idx + 64];
            ar[mt] = __builtin_bit_cast(long, va);
            ai[mt] = __builtin_bit_cast(long, vb);
            uint2 vn = make_uint2(vb.x ^ 0x80808080u, vb.y ^ 0x80808080u);
            ain[mt] = __builtin_bit_cast(long, vn);
        }
        long zr[2], zi_[2];
#pragma unroll
        for (int nt = 0; nt < 2; nt++) {
            int b = nt*16 + lo;
            int du = b*32 + ((kk*4 + hi) ^ (b & 7));
            zr[nt]  = __builtin_bit_cast(long, lz8[0][du]);
            zi_[nt] = __builtin_bit_cast(long, lz8[1][du]);
        }
#pragma unroll
        for (int mt = 0; mt < 2; mt++)
#pragma unroll
            for (int nt = 0; nt < 2; nt++) {
                accr[mt][nt] = __builtin_amdgcn_mfma_f32_16x16x32_fp8_fp8(ar[mt],  zr[nt],  accr[mt][nt], 0, 0, 0);
                accr[mt][nt] = __builtin_amdgcn_mfma_f32_16x16x32_fp8_fp8(ain[mt], zi_[nt], accr[mt][nt], 0, 0, 0);
                acci[mt][nt] = __builtin_amdgcn_mfma_f32_16x16x32_fp8_fp8(ar[mt],  zi_[nt], acci[mt][nt], 0, 0, 0);
                acci[mt][nt] = __builtin_amdgcn_mfma_f32_16x16x32_fp8_fp8(ai[mt],  zr[nt],  acci[mt][nt], 0, 0, 0);
            }
    }
    __syncthreads();
    // ---- epilogue 1: wx = z32 - 2 acc/S; write bf16 wx into LDS ----
#pragma unroll
    for (int mt = 0; mt < 2; mt++)
#pragma unroll
        for (int nt = 0; nt < 2; nt++) {
            int c0 = w*32 + mt*16 + hi*4;
            int b  = nt*16 + lo;
            size_t zb = ((size_t)f*NB + b)*NCH + c0;
            float4 z4r = *(const float4*)(z32r + zb);
            float4 z4i = *(const float4*)(z32i + zb);
            const float k2 = 2.f * INV_ASCALE;
            float vr[4] = { z4r.x - k2*accr[mt][nt][0], z4r.y - k2*accr[mt][nt][1],
                            z4r.z - k2*accr[mt][nt][2], z4r.w - k2*accr[mt][nt][3] };
            float vi[4] = { z4i.x - k2*acci[mt][nt][0], z4i.y - k2*acci[mt][nt][1],
                            z4i.z - k2*acci[mt][nt][2], z4i.w - k2*acci[mt][nt][3] };
            int o16c = c0 >> 3;
            int duc = b*32 + (o16c ^ (b & 7));
            int sel = (c0 >> 2) & 1;
            ((uint2*)&lw[0][duc])[sel] = make_uint2(pack2(vr[0], vr[1]), pack2(vr[2], vr[3]));
            ((uint2*)&lw[1][duc])[sel] = make_uint2(pack2(vi[0], vi[1]), pack2(vi[2], vi[3]));
        }
    __syncthreads();
    // ---- matmul 2: wxh = H * wx (bf16) ----
#pragma unroll
    for (int mt = 0; mt < 2; mt++)
#pragma unroll
        for (int nt = 0; nt < 2; nt++) { accr[mt][nt] = zz; acci[mt][nt] = zz; }
    for (int kk = 0; kk < 8; kk++) {
        bf16x8 hm[2];
#pragma unroll
        for (int mt = 0; mt < 2; mt++) {
            int mtg = w*2 + mt;
            hm[mt] = __builtin_bit_cast(bf16x8, H4[((size_t)kk*16 + mtg)*64 + lane]);
        }
        bf16x8 zr[2], zi_[2];
#pragma unroll
        for (int nt = 0; nt < 2; nt++) {
            int b = nt*16 + lo;
            int du = b*32 + ((kk*4 + hi) ^ (b & 7));
            zr[nt]  = __builtin_bit_cast(bf16x8, lw[0][du]);
            zi_[nt] = __builtin_bit_cast(bf16x8, lw[1][du]);
        }
#pragma unroll
        for (int mt = 0; mt < 2; mt++)
#pragma unroll
            for (int nt = 0; nt < 2; nt++) {
                accr[mt][nt] = __builtin_amdgcn_mfma_f32_16x16x32_bf16(hm[mt], zr[nt],  accr[mt][nt], 0, 0, 0);
                acci[mt][nt] = __builtin_amdgcn_mfma_f32_16x16x32_bf16(hm[mt], zi_[nt], acci[mt][nt], 0, 0, 0);
            }
    }
    // ---- epilogue 2: wxh bf16 planes, [f][b][o] layout ----
#pragma unroll
    for (int mt = 0; mt < 2; mt++)
#pragma unroll
        for (int nt = 0; nt < 2; nt++) {
            int o0 = w*32 + mt*16 + hi*4;
            int b  = nt*16 + lo;
            size_t zb = ((size_t)f*NB + b)*NCH + o0;
            *(uint2*)(wxhR + zb) = make_uint2(pack2(accr[mt][nt][0], accr[mt][nt][1]),
                                              pack2(accr[mt][nt][2], accr[mt][nt][3]));
            *(uint2*)(wxhI + zb) = make_uint2(pack2(acci[mt][nt][0], acci[mt][nt][1]),
                                              pack2(acci[mt][nt][2], acci[mt][nt][3]));
        }
}

// ---------------- pass I: complex ifft along i -> G[j][r][ob] (coalesced stores) ----------------
template<int RH>
__device__ __forceinline__ void ifft_i_body(const unsigned short* __restrict__ YR,
                                            const unsigned short* __restrict__ YI,
                                            float2* __restrict__ G, int j, int ob)
{
    float2 Gacc[16];
#pragma unroll
    for (int rr = 0; rr < 16; rr++) Gacc[rr] = make_float2(0.f, 0.f);
#pragma unroll
    for (int i = 0; i < 32; i++) {
        size_t yi_ = (size_t)(i * 17 + j) * 8192 + ob;
        float Yx = bf2f(YR[yi_]);
        float Yy = bf2f(YI[yi_]);
#pragma unroll
        for (int rr = 0; rr < 16; rr++) {
            int m = (i * (RH * 16 + rr)) & 31;     // compile-time constant
            Gacc[rr].x += Yx*COS32[m] - Yy*SIN32[m];
            Gacc[rr].y += Yx*SIN32[m] + Yy*COS32[m];
        }
    }
#pragma unroll
    for (int rr = 0; rr < 16; rr++) {
        G[((size_t)(j*32 + RH*16 + rr))*8192 + ob] =
            make_float2(Gacc[rr].x * (1.f/32.f), Gacc[rr].y * (1.f/32.f));
    }
}

__global__ __launch_bounds__(256) void ifft_i(const unsigned short* __restrict__ YR,
                                              const unsigned short* __restrict__ YI,
                                              float2* __restrict__ G) {
    int bid = blockIdx.x;
    int j   = bid >> 6;          // 0..16
    int rh  = (bid >> 5) & 1;    // 0..1
    int obc = bid & 31;          // 0..31
    int ob  = obc * 256 + threadIdx.x;
    if (rh == 0) ifft_i_body<0>(YR, YI, G, j, ob);
    else         ifft_i_body<1>(YR, YI, G, j, ob);
}

// ---------------- pass II: irfft along j + bias -> out[b][o][r][s] ----------------
__global__ __launch_bounds__(256) void irfft_j(const float2* __restrict__ G,
                                               const float* __restrict__ bias,
                                               float* __restrict__ out) {
    int gid = blockIdx.x * 256 + threadIdx.x;
    int r = gid >> 13, ob = gid & 8191;
    int b = ob >> 8, o = ob & 255;
    float2 Gv[17];
#pragma unroll
    for (int jj = 0; jj < 17; jj++)
        Gv[jj] = G[((size_t)(jj*32 + r))*8192 + ob];
    float y[32];
    float g0 = Gv[0].x, g16 = Gv[16].x;
#pragma unroll
    for (int s = 0; s < 32; s++) y[s] = g0 + ((s & 1) ? -g16 : g16);
#pragma unroll
    for (int jj = 1; jj < 16; jj++) {
#pragma unroll
        for (int s = 0; s < 32; s++) {
            int m = (jj * s) & 31;                 // compile-time constant
            y[s] += 2.f * (Gv[jj].x * COS32[m] - Gv[jj].y * SIN32[m]);
        }
    }
    float bv = bias[o];
    float* op = out + ((size_t)(b * NCH + o) * 32 + r) * 32;
#pragma unroll
    for (int s = 0; s < 32; s++) op[s] = y[s] * (1.f/32.f) + bv;
}

extern "C" void kernel_launch(void* const* d_in, const int* in_sizes, int n_in,
                              void* d_out, int out_size, void* d_ws, size_t ws_size,
                              hipStream_t stream) {
    (void)in_sizes; (void)n_in; (void)out_size;
    if (ws_size < WS_NEED) return;

    const float* x     = (const float*)d_in[0];
    const float* w     = (const float*)d_in[1];
    const float* alpha = (const float*)d_in[2];
    const float* H     = (const float*)d_in[3];
    const float* bias  = (const float*)d_in[4];
    float* out = (float*)d_out;

    char* ws = (char*)d_ws;
    unsigned char* Afrag = (unsigned char*)(ws + OFF_AFRAG);
    float2* tmp = (float2*)(ws + OFF_AFRAG);   // dead before a_build writes Afrag
    float2* G   = (float2*)(ws + OFF_AFRAG);   // live after neum passes (Afrag dead)
    unsigned char* t8r  = (unsigned char*)(ws + OFF_T8R);
    unsigned char* t8i  = (unsigned char*)(ws + OFF_T8I);
    unsigned char* z8r  = (unsigned char*)(ws + OFF_Z8R);
    unsigned char* z8i  = (unsigned char*)(ws + OFF_Z8I);
    float* z32r = (float*)(ws + OFF_Z32R);
    float* z32i = (float*)(ws + OFF_Z32I);
    unsigned short* wxhR = (unsigned short*)(ws + OFF_WXHR);
    unsigned short* wxhI = (unsigned short*)(ws + OFF_WXHI);
    unsigned short* Hfrag = (unsigned short*)(ws + OFF_HFRAG);
    float* red = (float*)(ws + OFF_RED);
    float* sig = red + 256;

    norm_part<<<256, 256, 0, stream>>>(w, red);
    norm_final<<<1, 256, 0, stream>>>(red, alpha, sig);
    hfrag_build<<<dim3(8, 16), 64, 0, stream>>>(H, Hfrag);

    rfft2_reg<<<1024, 256, 0, stream>>>(x, tmp);
    transpose_z<<<dim3(8, 17, 32), 256, 0, stream>>>(tmp, z32r, z32i, z8r, z8i);

    a_build_direct<<<dim3(16, 8, 17), 256, 0, stream>>>(w, sig, (unsigned int*)Afrag);
    neum1<<<NF*2, 256, 0, stream>>>(Afrag, z8r, z8i, t8r, t8i);
    neum2h<<<NF, 512, 0, stream>>>(Afrag, Hfrag, t8r, t8i, z32r, z32i, wxhR, wxhI);

    ifft_i<<<1088, 256, 0, stream>>>(wxhR, wxhI, G);
    irfft_j<<<1024, 256, 0, stream>>>(G, bias, out);
}

// Round 13
// 172.528 us; speedup vs baseline: 2.4212x; 1.0548x over previous
//
#include <hip/hip_runtime.h>
#include <hip/hip_fp8.h>
#include <cstddef>

#define PI_F 3.14159265358979323846f

#define NCH 256   // C
#define NB  32    // B
#define NF  544   // n*(n/2+1),  f = i*17 + j

#define ASCALE     65536.0f
#define INV_ASCALE (1.0f/65536.0f)

typedef short  bf16x8 __attribute__((ext_vector_type(8)));
typedef float  f32x4  __attribute__((ext_vector_type(4)));

// ---- workspace layout (bytes), single-chunk, fp8 A ----
#define SZ_AFRAG ((size_t)NF*8*16*1024)         // 71,303,168 (fp8 fragments; tmp & G alias)
#define SZ_P8    ((size_t)NF*NB*NCH)            // 4,456,448  (fp8 plane)
#define SZ_PB    ((size_t)NF*NB*NCH*2)          // 8,912,896  (bf16 plane)
#define SZ_P32   ((size_t)NF*NB*NCH*4)          // 17,825,792 (fp32 plane)
#define OFF_AFRAG ((size_t)0)
#define OFF_Z8R  (OFF_AFRAG + SZ_AFRAG)
#define OFF_Z8I  (OFF_Z8R + SZ_P8)
#define OFF_Z32R (OFF_Z8I + SZ_P8)
#define OFF_Z32I (OFF_Z32R + SZ_P32)
#define OFF_WXHR (OFF_Z32I + SZ_P32)
#define OFF_WXHI (OFF_WXHR + SZ_PB)
#define OFF_HFRAG (OFF_WXHI + SZ_PB)
#define SZ_HFRAG ((size_t)8*16*1024)            // 131,072
#define OFF_RED  (OFF_HFRAG + SZ_HFRAG)
#define WS_NEED  (OFF_RED + (size_t)4096)       // ~134 MB

// 32-point twiddle tables: COS32[k]=cos(2pi k/32), SIN32[k]=sin(2pi k/32)
__device__ constexpr float COS32[32] = {
     1.0000000000f,  0.9807852804f,  0.9238795325f,  0.8314696123f,
     0.7071067812f,  0.5555702330f,  0.3826834324f,  0.1950903220f,
     0.0000000000f, -0.1950903220f, -0.3826834324f, -0.5555702330f,
    -0.7071067812f, -0.8314696123f, -0.9238795325f, -0.9807852804f,
    -1.0000000000f, -0.9807852804f, -0.9238795325f, -0.8314696123f,
    -0.7071067812f, -0.5555702330f, -0.3826834324f, -0.1950903220f,
    -0.0000000000f,  0.1950903220f,  0.3826834324f,  0.5555702330f,
     0.7071067812f,  0.8314696123f,  0.9238795325f,  0.9807852804f };
__device__ constexpr float SIN32[32] = {
     0.0000000000f,  0.1950903220f,  0.3826834324f,  0.5555702330f,
     0.7071067812f,  0.8314696123f,  0.9238795325f,  0.9807852804f,
     1.0000000000f,  0.9807852804f,  0.9238795325f,  0.8314696123f,
     0.7071067812f,  0.5555702330f,  0.3826834324f,  0.1950903220f,
     0.0000000000f, -0.1950903220f, -0.3826834324f, -0.5555702330f,
    -0.7071067812f, -0.8314696123f, -0.9238795325f, -0.9807852804f,
    -1.0000000000f, -0.9807852804f, -0.9238795325f, -0.8314696123f,
    -0.7071067812f, -0.5555702330f, -0.3826834324f, -0.1950903220f };

__device__ __forceinline__ unsigned short f2bf(float x) {
    unsigned int u = __float_as_uint(x);
    u += 0x7FFFu + ((u >> 16) & 1u);            // RNE
    return (unsigned short)(u >> 16);
}
__device__ __forceinline__ float bf2f(unsigned int h) {
    return __uint_as_float(h << 16);
}
__device__ __forceinline__ unsigned int pack2(float a, float b) {
    return (unsigned int)f2bf(a) | ((unsigned int)f2bf(b) << 16);
}
__device__ __forceinline__ unsigned char f2e4m3(float x) {
    __hip_fp8_e4m3 h(x);
    return (unsigned char)h.__x;
}
__device__ __forceinline__ float e4m3f(unsigned int b) {
    __hip_fp8_e4m3 h; h.__x = (__hip_fp8_storage_t)b;
    return (float)h;
}
__device__ __forceinline__ unsigned int pk4_e4m3(const float* v) {
    return (unsigned)f2e4m3(v[0]) | ((unsigned)f2e4m3(v[1]) << 8) |
           ((unsigned)f2e4m3(v[2]) << 16) | ((unsigned)f2e4m3(v[3]) << 24);
}

// ---------------- norm of wfft (closed form via Parseval) ----------------
__global__ void norm_part(const float* __restrict__ w, float* __restrict__ red) {
    int idx = blockIdx.x * 256 + threadIdx.x;
    const float* wp = w + (size_t)idx * 9;
    float s2 = 0.f, aa = 0.f, bb = 0.f;
#pragma unroll
    for (int u = 0; u < 3; u++) {
        float w0 = wp[u*3+0], w1 = wp[u*3+1], w2 = wp[u*3+2];
        s2 += w0*w0 + w1*w1 + w2*w2;
        float au = w0 + w1 + w2, bu = w0 - w1 + w2;
        aa += au*au; bb += bu*bu;
    }
    float p = 512.f*s2 + 16.f*(aa + bb);
    __shared__ float sm[256];
    sm[threadIdx.x] = p; __syncthreads();
    for (int s = 128; s > 0; s >>= 1) {
        if (threadIdx.x < s) sm[threadIdx.x] += sm[threadIdx.x + s];
        __syncthreads();
    }
    if (threadIdx.x == 0) red[blockIdx.x] = sm[0];
}

__global__ void norm_final(const float* __restrict__ red, const float* __restrict__ alpha,
                           float* __restrict__ sig) {
    __shared__ float sm[256];
    sm[threadIdx.x] = red[threadIdx.x]; __syncthreads();
    for (int s = 128; s > 0; s >>= 1) {
        if (threadIdx.x < s) sm[threadIdx.x] += sm[threadIdx.x + s];
        __syncthreads();
    }
    if (threadIdx.x == 0) sig[0] = alpha[0] / sqrtf(sm[0]);
}

// ---------------- H fragments (A-operand: m=o, k=c), bf16 ----------------
__global__ void hfrag_build(const float* __restrict__ H, unsigned short* __restrict__ Hfrag) {
    int kk = blockIdx.x, mt = blockIdx.y, lane = threadIdx.x;   // 64 threads
    int o = mt*16 + (lane & 15), c0 = kk*32 + (lane >> 4)*8;
    const float* hp = H + (size_t)o*NCH + c0;
    uint4 u;
    u.x = pack2(hp[0], hp[1]); u.y = pack2(hp[2], hp[3]);
    u.z = pack2(hp[4], hp[5]); u.w = pack2(hp[6], hp[7]);
    ((uint4*)Hfrag)[((size_t)kk*16 + mt)*64 + lane] = u;
}

// ---------------- rfft2: register-resident DFT, 8 tiles per 256-thread block ----------------
// Output staged through LDS Z for coalesced 2KB-contiguous global stores (R12:
// direct per-lane 8B strided stores caused ~2x write amplification).
// NOTE: no min-waves arg — (256,4) forced VGPR 64 and spilled (R9: 4x slower).
__global__ __launch_bounds__(256) void rfft2_reg(const float* __restrict__ x,
                                                 float2* __restrict__ tmp)
{
    __shared__ float2 T[8][544];       // [half][r*17+j], ~35 KB
    __shared__ float2 Z[8][544];       // output staging, ~35 KB
    __shared__ float wc[32], wsn[32];
    int t = threadIdx.x;
    int half = t >> 5, lane = t & 31;
    int cb = blockIdx.x * 8 + half;    // tile index in tmp order: cb = c*32 + b
    int c = cb >> 5, b = cb & 31;
    if (t < 32) { wc[t] = COS32[t]; wsn[t] = SIN32[t]; }
    float xr[32];
    const float* xp = x + ((size_t)(b * NCH + c)) * 1024 + lane * 32;
#pragma unroll
    for (int q = 0; q < 8; q++) {
        float4 v = *(const float4*)(xp + q*4);
        xr[q*4+0] = v.x; xr[q*4+1] = v.y; xr[q*4+2] = v.z; xr[q*4+3] = v.w;
    }
    float x0v = xr[0], x16v = xr[16];
    float es[15], os[15];
#pragma unroll
    for (int s = 1; s <= 15; s++) { es[s-1] = xr[s] + xr[32-s]; os[s-1] = xr[s] - xr[32-s]; }
#pragma unroll
    for (int j = 0; j < 17; j++) {
        float ax = x0v + ((j & 1) ? -x16v : x16v);
        float ay = 0.f;
#pragma unroll
        for (int s = 1; s <= 15; s++) {
            int m = (j * s) & 31;
            ax += es[s-1] * COS32[m];
            ay -= os[s-1] * SIN32[m];
        }
        T[half][lane*17 + j] = make_float2(ax, ay);
    }
    __syncthreads();
    float wr_[16], wi_[16];
#pragma unroll
    for (int r = 0; r < 16; r++) {
        int m = (lane * r) & 31;
        wr_[r] = wc[m]; wi_[r] = wsn[m];
    }
    float sgn = (lane & 1) ? -1.f : 1.f;    // (-1)^i
#pragma unroll
    for (int j = 0; j < 17; j++) {
        float ax = 0.f, ay = 0.f;
#pragma unroll
        for (int r = 0; r < 16; r++) {
            float2 t1 = T[half][r*17 + j];
            float2 t2 = T[half][(r+16)*17 + j];
            float ex = fmaf(sgn, t2.x, t1.x);
            float ey = fmaf(sgn, t2.y, t1.y);
            ax += ex * wr_[r] + ey * wi_[r];
            ay += ey * wr_[r] - ex * wi_[r];
        }
        Z[half][lane*17 + j] = make_float2(ax, ay);
    }
    __syncthreads();
    // cooperative coalesced copy-out: Z layout == tmp[cb][f] for this block
    float2* outp = tmp + (size_t)blockIdx.x * 8 * 544;
    const float2* zf = (const float2*)Z;
#pragma unroll
    for (int u = 0; u < 17; u++)
        outp[u*256 + t] = zf[u*256 + t];
}

// ---------------- transpose tmp[cb][f] -> fp32 planes + fp8 planes [f][b][c] ----------------
__global__ __launch_bounds__(256) void transpose_z(const float2* __restrict__ tmp,
        float* __restrict__ z32r, float* __restrict__ z32i,
        unsigned char* __restrict__ z8r, unsigned char* __restrict__ z8i)
{
    __shared__ float2 tile[32][33];
    int ct = blockIdx.x, ft = blockIdx.y, b = blockIdx.z;
    int t = threadIdx.x;
#pragma unroll
    for (int it = 0; it < 4; it++) {
        int idx = t + it*256; int cl = idx >> 5, fl = idx & 31;
        tile[cl][fl] = tmp[((size_t)((ct*32 + cl)*32 + b))*544 + ft*32 + fl];
    }
    __syncthreads();
#pragma unroll
    for (int it = 0; it < 4; it++) {
        int idx = t + it*256; int fl = idx >> 5, cl = idx & 31;
        float2 v = tile[cl][fl];
        size_t zi_ = ((size_t)(ft*32 + fl)*NB + b)*NCH + ct*32 + cl;
        z32r[zi_] = v.x; z32i[zi_] = v.y;
        z8r[zi_] = f2e4m3(v.x); z8i[zi_] = f2e4m3(v.y);
    }
}

// ---------------- A-build, factorized + direct fragment writes ----------------
__global__ __launch_bounds__(256) void a_build_direct(const float* __restrict__ w,
        const float* __restrict__ sig, unsigned int* __restrict__ Afrag)
{
    int mt = blockIdx.x, kk = blockIdx.y, j = blockIdx.z;   // 16, 8, 17
    int t = threadIdx.x;
    int wv = t & 127;
    int c   = mt*16 + ((wv >> 1) & 15);
    int cp0 = kk*32 + (wv >> 5)*8 + (wv & 1)*4;
    bool isReal = (t < 128);
    float sS = sig[0] * ASCALE;
    float sgnS = isReal ? sS : -sS;
    f32x4 P1, P2, P3, P4, P5;
#pragma unroll
    for (int e = 0; e < 4; e++) {
        int cp = cp0 + e;
        const float* p1 = w + ((size_t)c*NCH + cp)*9;
        const float* p2 = w + ((size_t)cp*NCH + c)*9;
        float u_[9];
#pragma unroll
        for (int q = 0; q < 9; q++)
            u_[q] = isReal ? (p1[q] - p2[q]) : (p1[q] + p2[q]);
        if (isReal) {
            P1[e] = sgnS * u_[4];
            P2[e] = sgnS * (u_[3] + u_[5]);
            P3[e] = sgnS * (u_[1] + u_[7]);
            P4[e] = sgnS * (u_[0] + u_[2] + u_[6] + u_[8]);
            P5[e] = sgnS * ((u_[6] - u_[8]) - (u_[0] - u_[2]));
        } else {
            P1[e] = sgnS * (u_[3] - u_[5]);
            P2[e] = sgnS * ((u_[0] - u_[2]) + (u_[6] - u_[8]));
            P3[e] = sgnS * (u_[1] - u_[7]);
            P4[e] = sgnS * ((u_[0] + u_[2]) - (u_[6] + u_[8]));
            P5[e] = 0.f;
        }
    }
    float cps = COS32[j], sns = SIN32[j];
    f32x4 Aj, Bj, Cj;
    if (isReal) { Aj = P1 + cps*P2; Bj = P3 + cps*P4; Cj = sns*P5; }
    else        { Aj = sns*P1;      Bj = sns*P2;      Cj = P3 + cps*P4; }
    unsigned int* out = Afrag + ((size_t)j*128 + kk*16 + mt)*256 + t;
#pragma unroll
    for (int i = 0; i < 32; i++) {
        f32x4 v = Aj + COS32[i]*Bj + SIN32[i]*Cj;   // compile-time twiddles
        *out = (unsigned)f2e4m3(v[0]) | ((unsigned)f2e4m3(v[1]) << 8)
             | ((unsigned)f2e4m3(v[2]) << 16) | ((unsigned)f2e4m3(v[3]) << 24);
        out += (size_t)17*32768;   // fl = i*17 + j
    }
}

// ---------------- neum_fused: t = z - A z ; wx = z32 - 2 A t ; wxh = H wx ----------------
// One block per f (512 thr). A read twice (2nd is L2-warm); t lives only in LDS.
__global__ __launch_bounds__(512) void neum_fused(
    const unsigned char* __restrict__ Afrag,
    const unsigned short* __restrict__ Hfrag,
    const unsigned char* __restrict__ z8r, const unsigned char* __restrict__ z8i,
    const float* __restrict__ z32r, const float* __restrict__ z32i,
    unsigned short* __restrict__ wxhR, unsigned short* __restrict__ wxhI)
{
    __shared__ uint2 lz8[2][1024];   // 16 KB: fp8 z, then fp8 t (in-place)
    __shared__ uint4 lw[2][1024];    // 32 KB: bf16 wx
    int fl = blockIdx.x;
    int f = fl;
    int t = threadIdx.x;
    const uint2* s0 = (const uint2*)(z8r + (size_t)f*8192);
    const uint2* s1 = (const uint2*)(z8i + (size_t)f*8192);
    for (int u = t; u < 2048; u += 512) {
        int p = u >> 10, idx = u & 1023;
        int b = idx >> 5, o16 = idx & 31;
        lz8[p][b*32 + (o16 ^ (b & 7))] = (p ? s1 : s0)[idx];
    }
    __syncthreads();
    int w = t >> 6, lane = t & 63, lo = lane & 15, hi = lane >> 4;
    const uint2* A8 = (const uint2*)Afrag;
    const uint4* H4 = (const uint4*)Hfrag;
    f32x4 accr[2][2], acci[2][2];
    f32x4 zz = {0.f, 0.f, 0.f, 0.f};
#pragma unroll
    for (int mt = 0; mt < 2; mt++)
#pragma unroll
        for (int nt = 0; nt < 2; nt++) { accr[mt][nt] = zz; acci[mt][nt] = zz; }
    // ---- matmul 1: acc = A * z (fp8) ----
    for (int kk = 0; kk < 8; kk++) {
        long ar[2], ai[2], ain[2];
#pragma unroll
        for (int mt = 0; mt < 2; mt++) {
            int mtg = w*2 + mt;
            size_t idx = (((size_t)fl*8 + kk)*16 + mtg)*128 + lane;
            uint2 va = A8[idx], vb = A8[idx + 64];
            ar[mt] = __builtin_bit_cast(long, va);
            ai[mt] = __builtin_bit_cast(long, vb);
            uint2 vn = make_uint2(vb.x ^ 0x80808080u, vb.y ^ 0x80808080u);
            ain[mt] = __builtin_bit_cast(long, vn);
        }
        long zr[2], zi_[2];
#pragma unroll
        for (int nt = 0; nt < 2; nt++) {
            int b = nt*16 + lo;
            int du = b*32 + ((kk*4 + hi) ^ (b & 7));
            zr[nt]  = __builtin_bit_cast(long, lz8[0][du]);
            zi_[nt] = __builtin_bit_cast(long, lz8[1][du]);
        }
#pragma unroll
        for (int mt = 0; mt < 2; mt++)
#pragma unroll
            for (int nt = 0; nt < 2; nt++) {
                accr[mt][nt] = __builtin_amdgcn_mfma_f32_16x16x32_fp8_fp8(ar[mt],  zr[nt],  accr[mt][nt], 0, 0, 0);
                accr[mt][nt] = __builtin_amdgcn_mfma_f32_16x16x32_fp8_fp8(ain[mt], zi_[nt], accr[mt][nt], 0, 0, 0);
                acci[mt][nt] = __builtin_amdgcn_mfma_f32_16x16x32_fp8_fp8(ar[mt],  zi_[nt], acci[mt][nt], 0, 0, 0);
                acci[mt][nt] = __builtin_amdgcn_mfma_f32_16x16x32_fp8_fp8(ai[mt],  zr[nt],  acci[mt][nt], 0, 0, 0);
            }
    }
    __syncthreads();   // all waves done reading z from LDS
    // ---- epilogue 1: t = z - Az/S, fp8, written IN PLACE over z (own 4B span only) ----
#pragma unroll
    for (int mt = 0; mt < 2; mt++)
#pragma unroll
        for (int nt = 0; nt < 2; nt++) {
            int c0 = w*32 + mt*16 + hi*4;
            int b  = nt*16 + lo;
            int duc = b*32 + ((c0 >> 3) ^ (b & 7));
            int sel = (c0 >> 2) & 1;
            uint2 q0 = lz8[0][duc], q1 = lz8[1][duc];
            unsigned qr = sel ? q0.y : q0.x;
            unsigned qi = sel ? q1.y : q1.x;
            float zfr[4] = { e4m3f(qr & 0xffu), e4m3f((qr>>8)&0xffu),
                             e4m3f((qr>>16)&0xffu), e4m3f(qr>>24) };
            float zfi[4] = { e4m3f(qi & 0xffu), e4m3f((qi>>8)&0xffu),
                             e4m3f((qi>>16)&0xffu), e4m3f(qi>>24) };
            float vr[4], vi[4];
#pragma unroll
            for (int jj = 0; jj < 4; jj++) {
                vr[jj] = zfr[jj] - accr[mt][nt][jj] * INV_ASCALE;
                vi[jj] = zfi[jj] - acci[mt][nt][jj] * INV_ASCALE;
            }
            ((unsigned int*)&lz8[0][duc])[sel] = pk4_e4m3(vr);
            ((unsigned int*)&lz8[1][duc])[sel] = pk4_e4m3(vi);
        }
    __syncthreads();
    // ---- matmul 2: acc = A * t (fp8, A re-read — L2-warm) ----
#pragma unroll
    for (int mt = 0; mt < 2; mt++)
#pragma unroll
        for (int nt = 0; nt < 2; nt++) { accr[mt][nt] = zz; acci[mt][nt] = zz; }
    for (int kk = 0; kk < 8; kk++) {
        long ar[2], ai[2], ain[2];
#pragma unroll
        for (int mt = 0; mt < 2; mt++) {
            int mtg = w*2 + mt;
            size_t idx = (((size_t)fl*8 + kk)*16 + mtg)*128 + lane;
            uint2 va = A8[idx], vb = A8[idx + 64];
            ar[mt] = __builtin_bit_cast(long, va);
            ai[mt] = __builtin_bit_cast(long, vb);
            uint2 vn = make_uint2(vb.x ^ 0x80808080u, vb.y ^ 0x80808080u);
            ain[mt] = __builtin_bit_cast(long, vn);
        }
        long zr[2], zi_[2];
#pragma unroll
        for (int nt = 0; nt < 2; nt++) {
            int b = nt*16 + lo;
            int du = b*32 + ((kk*4 + hi) ^ (b & 7));
            zr[nt]  = __builtin_bit_cast(long, lz8[0][du]);
            zi_[nt] = __builtin_bit_cast(long, lz8[1][du]);
        }
#pragma unroll
        for (int mt = 0; mt < 2; mt++)
#pragma unroll
            for (int nt = 0; nt < 2; nt++) {
                accr[mt][nt] = __builtin_amdgcn_mfma_f32_16x16x32_fp8_fp8(ar[mt],  zr[nt],  accr[mt][nt], 0, 0, 0);
                accr[mt][nt] = __builtin_amdgcn_mfma_f32_16x16x32_fp8_fp8(ain[mt], zi_[nt], accr[mt][nt], 0, 0, 0);
                acci[mt][nt] = __builtin_amdgcn_mfma_f32_16x16x32_fp8_fp8(ar[mt],  zi_[nt], acci[mt][nt], 0, 0, 0);
                acci[mt][nt] = __builtin_amdgcn_mfma_f32_16x16x32_fp8_fp8(ai[mt],  zr[nt],  acci[mt][nt], 0, 0, 0);
            }
    }
    __syncthreads();   // all waves done reading t from LDS
    // ---- epilogue 2: wx = z32 - 2 acc/S; write bf16 wx into LDS ----
#pragma unroll
    for (int mt = 0; mt < 2; mt++)
#pragma unroll
        for (int nt = 0; nt < 2; nt++) {
            int c0 = w*32 + mt*16 + hi*4;
            int b  = nt*16 + lo;
            size_t zb = ((size_t)f*NB + b)*NCH + c0;
            float4 z4r = *(const float4*)(z32r + zb);
            float4 z4i = *(const float4*)(z32i + zb);
            const float k2 = 2.f * INV_ASCALE;
            float vr[4] = { z4r.x - k2*accr[mt][nt][0], z4r.y - k2*accr[mt][nt][1],
                            z4r.z - k2*accr[mt][nt][2], z4r.w - k2*accr[mt][nt][3] };
            float vi[4] = { z4i.x - k2*acci[mt][nt][0], z4i.y - k2*acci[mt][nt][1],
                            z4i.z - k2*acci[mt][nt][2], z4i.w - k2*acci[mt][nt][3] };
            int o16c = c0 >> 3;
            int duc = b*32 + (o16c ^ (b & 7));
            int sel = (c0 >> 2) & 1;
            ((uint2*)&lw[0][duc])[sel] = make_uint2(pack2(vr[0], vr[1]), pack2(vr[2], vr[3]));
            ((uint2*)&lw[1][duc])[sel] = make_uint2(pack2(vi[0], vi[1]), pack2(vi[2], vi[3]));
        }
    __syncthreads();
    // ---- matmul 3: wxh = H * wx (bf16) ----
#pragma unroll
    for (int mt = 0; mt < 2; mt++)
#pragma unroll
        for (int nt = 0; nt < 2; nt++) { accr[mt][nt] = zz; acci[mt][nt] = zz; }
    for (int kk = 0; kk < 8; kk++) {
        bf16x8 hm[2];
#pragma unroll
        for (int mt = 0; mt < 2; mt++) {
            int mtg = w*2 + mt;
            hm[mt] = __builtin_bit_cast(bf16x8, H4[((size_t)kk*16 + mtg)*64 + lane]);
        }
        bf16x8 zr[2], zi_[2];
#pragma unroll
        for (int nt = 0; nt < 2; nt++) {
            int b = nt*16 + lo;
            int du = b*32 + ((kk*4 + hi) ^ (b & 7));
            zr[nt]  = __builtin_bit_cast(bf16x8, lw[0][du]);
            zi_[nt] = __builtin_bit_cast(bf16x8, lw[1][du]);
        }
#pragma unroll
        for (int mt = 0; mt < 2; mt++)
#pragma unroll
            for (int nt = 0; nt < 2; nt++) {
                accr[mt][nt] = __builtin_amdgcn_mfma_f32_16x16x32_bf16(hm[mt], zr[nt],  accr[mt][nt], 0, 0, 0);
                acci[mt][nt] = __builtin_amdgcn_mfma_f32_16x16x32_bf16(hm[mt], zi_[nt], acci[mt][nt], 0, 0, 0);
            }
    }
    // ---- epilogue 3: wxh bf16 planes, [f][b][o] layout ----
#pragma unroll
    for (int mt = 0; mt < 2; mt++)
#pragma unroll
        for (int nt = 0; nt < 2; nt++) {
            int o0 = w*32 + mt*16 + hi*4;
            int b  = nt*16 + lo;
            size_t zb = ((size_t)f*NB + b)*NCH + o0;
            *(uint2*)(wxhR + zb) = make_uint2(pack2(accr[mt][nt][0], accr[mt][nt][1]),
                                              pack2(accr[mt][nt][2], accr[mt][nt][3]));
            *(uint2*)(wxhI + zb) = make_uint2(pack2(acci[mt][nt][0], acci[mt][nt][1]),
                                              pack2(acci[mt][nt][2], acci[mt][nt][3]));
        }
}

// ---------------- pass I: complex ifft along i -> G[j][r][ob] (coalesced stores) ----------------
template<int RH>
__device__ __forceinline__ void ifft_i_body(const unsigned short* __restrict__ YR,
                                            const unsigned short* __restrict__ YI,
                                            float2* __restrict__ G, int j, int ob)
{
    float2 Gacc[16];
#pragma unroll
    for (int rr = 0; rr < 16; rr++) Gacc[rr] = make_float2(0.f, 0.f);
#pragma unroll
    for (int i = 0; i < 32; i++) {
        size_t yi_ = (size_t)(i * 17 + j) * 8192 + ob;
        float Yx = bf2f(YR[yi_]);
        float Yy = bf2f(YI[yi_]);
#pragma unroll
        for (int rr = 0; rr < 16; rr++) {
            int m = (i * (RH * 16 + rr)) & 31;     // compile-time constant
            Gacc[rr].x += Yx*COS32[m] - Yy*SIN32[m];
            Gacc[rr].y += Yx*SIN32[m] + Yy*COS32[m];
        }
    }
#pragma unroll
    for (int rr = 0; rr < 16; rr++) {
        G[((size_t)(j*32 + RH*16 + rr))*8192 + ob] =
            make_float2(Gacc[rr].x * (1.f/32.f), Gacc[rr].y * (1.f/32.f));
    }
}

__global__ __launch_bounds__(256) void ifft_i(const unsigned short* __restrict__ YR,
                                              const unsigned short* __restrict__ YI,
                                              float2* __restrict__ G) {
    int bid = blockIdx.x;
    int j   = bid >> 6;          // 0..16
    int rh  = (bid >> 5) & 1;    // 0..1
    int obc = bid & 31;          // 0..31
    int ob  = obc * 256 + threadIdx.x;
    if (rh == 0) ifft_i_body<0>(YR, YI, G, j, ob);
    else         ifft_i_body<1>(YR, YI, G, j, ob);
}

// ---------------- pass II: irfft along j + bias -> out[b][o][r][s] ----------------
__global__ __launch_bounds__(256) void irfft_j(const float2* __restrict__ G,
                                               const float* __restrict__ bias,
                                               float* __restrict__ out) {
    int gid = blockIdx.x * 256 + threadIdx.x;
    int r = gid >> 13, ob = gid & 8191;
    int b = ob >> 8, o = ob & 255;
    float2 Gv[17];
#pragma unroll
    for (int jj = 0; jj < 17; jj++)
        Gv[jj] = G[((size_t)(jj*32 + r))*8192 + ob];
    float y[32];
    float g0 = Gv[0].x, g16 = Gv[16].x;
#pragma unroll
    for (int s = 0; s < 32; s++) y[s] = g0 + ((s & 1) ? -g16 : g16);
#pragma unroll
    for (int jj = 1; jj < 16; jj++) {
#pragma unroll
        for (int s = 0; s < 32; s++) {
            int m = (jj * s) & 31;                 // compile-time constant
            y[s] += 2.f * (Gv[jj].x * COS32[m] - Gv[jj].y * SIN32[m]);
        }
    }
    float bv = bias[o];
    float* op = out + ((size_t)(b * NCH + o) * 32 + r) * 32;
#pragma unroll
    for (int s = 0; s < 32; s++) op[s] = y[s] * (1.f/32.f) + bv;
}

extern "C" void kernel_launch(void* const* d_in, const int* in_sizes, int n_in,
                              void* d_out, int out_size, void* d_ws, size_t ws_size,
                              hipStream_t stream) {
    (void)in_sizes; (void)n_in; (void)out_size;
    if (ws_size < WS_NEED) return;

    const float* x     = (const float*)d_in[0];
    const float* w     = (const float*)d_in[1];
    const float* alpha = (const float*)d_in[2];
    const float* H     = (const float*)d_in[3];
    const float* bias  = (const float*)d_in[4];
    float* out = (float*)d_out;

    char* ws = (char*)d_ws;
    unsigned char* Afrag = (unsigned char*)(ws + OFF_AFRAG);
    float2* tmp = (float2*)(ws + OFF_AFRAG);   // dead before a_build writes Afrag
    float2* G   = (float2*)(ws + OFF_AFRAG);   // live after neum pass (Afrag dead)
    unsigned char* z8r  = (unsigned char*)(ws + OFF_Z8R);
    unsigned char* z8i  = (unsigned char*)(ws + OFF_Z8I);
    float* z32r = (float*)(ws + OFF_Z32R);
    float* z32i = (float*)(ws + OFF_Z32I);
    unsigned short* wxhR = (unsigned short*)(ws + OFF_WXHR);
    unsigned short* wxhI = (unsigned short*)(ws + OFF_WXHI);
    unsigned short* Hfrag = (unsigned short*)(ws + OFF_HFRAG);
    float* red = (float*)(ws + OFF_RED);
    float* sig = red + 256;

    norm_part<<<256, 256, 0, stream>>>(w, red);
    norm_final<<<1, 256, 0, stream>>>(red, alpha, sig);
    hfrag_build<<<dim3(8, 16), 64, 0, stream>>>(H, Hfrag);

    rfft2_reg<<<1024, 256, 0, stream>>>(x, tmp);
    transpose_z<<<dim3(8, 17, 32), 256, 0, stream>>>(tmp, z32r, z32i, z8r, z8i);

    a_build_direct<<<dim3(16, 8, 17), 256, 0, stream>>>(w, sig, (unsigned int*)Afrag);
    neum_fused<<<NF, 512, 0, stream>>>(Afrag, Hfrag, z8r, z8i, z32r, z32i, wxhR, wxhI);

    ifft_i<<<1088, 256, 0, stream>>>(wxhR, wxhI, G);
    irfft_j<<<1024, 256, 0, stream>>>(G, bias, out);
}